// Round 7
// baseline (1131.459 us; speedup 1.0000x reference)
//
#include <hip/hip_runtime.h>

typedef short short8v __attribute__((ext_vector_type(8)));
typedef float f32x4 __attribute__((ext_vector_type(4)));
typedef _Float16 h4v __attribute__((ext_vector_type(4)));

__device__ __forceinline__ unsigned short f2bf(float f){
  unsigned int u = __float_as_uint(f);
  u += 0x7fffu + ((u >> 16) & 1u);
  return (unsigned short)(u >> 16);
}
__device__ __forceinline__ float bf2f(unsigned short h){
  return __uint_as_float(((unsigned int)h) << 16);
}
union H2F { unsigned short u; _Float16 h; };
__device__ __forceinline__ float fp16f(unsigned short b){ H2F t; t.u = b; return (float)t.h; }

typedef __attribute__((address_space(1))) const unsigned int gu32;
typedef __attribute__((address_space(3))) unsigned int lu32;
__device__ __forceinline__ void gl16(const void* g, void* l){
  __builtin_amdgcn_global_load_lds((gu32*)g, (lu32*)l, 16, 0, 0);
}

// ========== 256x256 GEMM: C = A @ B^T, bf16 in; 4-phase staggered prefetch (proven schedule) ==========
// EPI 0: +bias -> f32 (fc2) | EPI 3: +bias -> fp16 unit-packed (G)
template<int EPI>
__global__ __launch_bounds__(512, 2)
void gemm256(const unsigned short* __restrict__ A, const unsigned short* __restrict__ B,
             void* __restrict__ Cout, int M, int N, int K, int lda, int ldb, int ldc,
             const float* __restrict__ bias)
{
  __shared__ __align__(16) unsigned short As[2 * 2 * 256 * 32];   // 64 KB
  __shared__ __align__(16) unsigned short Bs[2 * 2 * 256 * 32];   // 64 KB

  const int tid = threadIdx.x;
  const int gx = gridDim.x;
  const int nwg = gx * gridDim.y;
  int dd = blockIdx.y * gx + blockIdx.x;
  int q8 = nwg >> 3, r8 = nwg & 7, xc = dd & 7, t8 = dd >> 3;
  int Lid = (xc < r8 ? xc * (q8 + 1) : r8 * (q8 + 1) + (xc - r8) * q8) + t8;
  const int bcol = (Lid % gx) * 256;
  const int brow = (Lid / gx) * 256;

  const int l = tid & 63, w = tid >> 6;
  const int wr = w >> 2;                 // M half (0..1)
  const int wn = w & 3;                  // N quarter (0..3)
  const int r16 = l & 15, kg = l >> 4;
  const int swz = (r16 >> 1) & 3;
  const int srow4 = l >> 2, sblk = l & 3;
  const int scol = (sblk ^ ((l >> 3) & 3)) * 8;

  const int kz = blockIdx.z * K;
  const unsigned short* Ag = A + (size_t)(brow + w * 32 + srow4) * lda + kz + scol;
  const unsigned short* Bg = B + (size_t)(bcol + w * 32 + srow4) * ldb + kz + scol;
  unsigned short* Asd = As + w * 1024;
  unsigned short* Bsd = Bs + w * 1024;

#define STA(buf, kh, kt) do { \
    gl16(Ag + (size_t)(kt) * 64 + (kh) * 32, Asd + (buf) * 16384 + (kh) * 8192); \
    gl16(Ag + (size_t)(kt) * 64 + (kh) * 32 + (size_t)16 * lda, Asd + (buf) * 16384 + (kh) * 8192 + 512); \
  } while (0)
#define STB(buf, kh, kt) do { \
    gl16(Bg + (size_t)(kt) * 64 + (kh) * 32, Bsd + (buf) * 16384 + (kh) * 8192); \
    gl16(Bg + (size_t)(kt) * 64 + (kh) * 32 + (size_t)16 * ldb, Bsd + (buf) * 16384 + (kh) * 8192 + 512); \
  } while (0)

  const unsigned short* Ard = As + (wr * 128 + r16) * 32 + ((kg ^ swz) * 8);
  const unsigned short* Brd = Bs + (wn * 64 + r16) * 32 + ((kg ^ swz) * 8);

  f32x4 acc[8][4];
  #pragma unroll
  for (int m = 0; m < 8; m++)
    #pragma unroll
    for (int nn = 0; nn < 4; nn++) { f32x4 z = {0.f, 0.f, 0.f, 0.f}; acc[m][nn] = z; }

  short8v af[4], bfr[4];

#define LDA4(c, kk, mq) { \
    _Pragma("unroll") for (int i = 0; i < 4; i++) \
      af[i] = *(const short8v*)(Ard + (c) * 16384 + (kk) * 8192 + ((mq) * 4 + i) * 512); }
#define LDB4(c, kk) { \
    _Pragma("unroll") for (int nn = 0; nn < 4; nn++) \
      bfr[nn] = *(const short8v*)(Brd + (c) * 16384 + (kk) * 8192 + nn * 512); }
#define MFMAQ(mq) { \
    __builtin_amdgcn_s_setprio(1); \
    _Pragma("unroll") for (int i = 0; i < 4; i++) { \
      _Pragma("unroll") for (int nn = 0; nn < 4; nn++) \
        acc[(mq) * 4 + i][nn] = __builtin_amdgcn_mfma_f32_16x16x32_bf16(af[i], bfr[nn], acc[(mq) * 4 + i][nn], 0, 0, 0); \
    } \
    __builtin_amdgcn_s_setprio(0); }

  const int nk = K >> 6;
  STA(0, 0, 0); STB(0, 0, 0); STA(0, 1, 0); STB(0, 1, 0);
  asm volatile("s_waitcnt vmcnt(4)" ::: "memory");
  __builtin_amdgcn_s_barrier();
  __builtin_amdgcn_sched_barrier(0);

  for (int j = 0; j < nk; j++) {
    const int c = j & 1, nb = c ^ 1;
    const bool pf = (j + 1 < nk);
    // phase 1
    LDB4(c, 0); LDA4(c, 0, 0);
    if (pf) STA(nb, 0, j + 1);
    __builtin_amdgcn_s_barrier();
    MFMAQ(0);
    __builtin_amdgcn_s_barrier();
    // phase 2
    LDA4(c, 0, 1);
    if (pf) STB(nb, 0, j + 1);
    __builtin_amdgcn_s_barrier();
    MFMAQ(1);
    if (pf) asm volatile("s_waitcnt vmcnt(4)" ::: "memory");
    else    asm volatile("s_waitcnt vmcnt(0)" ::: "memory");
    __builtin_amdgcn_s_barrier();
    __builtin_amdgcn_sched_barrier(0);
    // phase 3
    LDB4(c, 1); LDA4(c, 1, 0);
    if (pf) STA(nb, 1, j + 1);
    __builtin_amdgcn_s_barrier();
    MFMAQ(0);
    __builtin_amdgcn_s_barrier();
    // phase 4
    LDA4(c, 1, 1);
    if (pf) STB(nb, 1, j + 1);
    __builtin_amdgcn_s_barrier();
    MFMAQ(1);
    if (pf) asm volatile("s_waitcnt vmcnt(4)" ::: "memory");
    __builtin_amdgcn_s_barrier();
    __builtin_amdgcn_sched_barrier(0);
  }
#undef STA
#undef STB
#undef LDA4
#undef LDB4
#undef MFMAQ

  // C/D map: col = lane&15, row = (lane>>4)*4 + reg
  #pragma unroll
  for (int m = 0; m < 8; m++) {
    const int row0 = brow + wr * 128 + m * 16 + kg * 4;
    #pragma unroll
    for (int nn = 0; nn < 4; nn++) {
      const int col = bcol + wn * 64 + nn * 16 + r16;
      if (col < N) {
        const float bv = bias[col];
        #pragma unroll
        for (int rr = 0; rr < 4; rr++) {
          const int row = row0 + rr;
          if (row < M) {
            float val = acc[m][nn][rr] + bv;
            if (EPI == 3) {
              int dL = col >> 11, rc = col & 2047;
              int cg = rc >> 6, g = (rc >> 4) & 3, u = rc & 15;
              int pc = (dL << 11) + (((cg << 4) + u) << 2) + g;
              ((_Float16*)Cout)[(size_t)row * ldc + pc] = (_Float16)val;
            } else {
              ((float*)Cout)[(size_t)row * ldc + col] = val;
            }
          }
        }
      }
    }
  }
}

// ========== fc1: 128x128 tile, 8 waves (64x32 each), BK=64 dbuf, 64KB LDS -> 2 WGs/CU ==========
// A is raw f32: reg-stage 4x dwordx4 -> cvt_pk -> 2x b128 ds_write (round-0 swizzle layout).
// B via gl16 with the proven round-0 pre-swizzle. ONE barrier per K-tile (double-buffered).
// Counted vmcnt(2) retires A with a full compute phase of slack; 2-WG/CU overlap hides stalls.
__global__ __launch_bounds__(512, 4)
void gemm128fA(const float* __restrict__ A, const unsigned short* __restrict__ B,
               _Float16* __restrict__ Cout, int M, int N, int K, int lda, int ldb, int ldc,
               int nvalid)
{
  __shared__ __align__(16) unsigned short As[2 * 128 * 64];   // 32 KB
  __shared__ __align__(16) unsigned short Bs[2 * 128 * 64];   // 32 KB

  const int tid = threadIdx.x;
  const int gx = gridDim.x;
  const int nwg = gx * gridDim.y;
  int dd = blockIdx.y * gx + blockIdx.x;
  int q8 = nwg >> 3, r8 = nwg & 7, xc = dd & 7, t8 = dd >> 3;
  int Lid = (xc < r8 ? xc * (q8 + 1) : r8 * (q8 + 1) + (xc - r8) * q8) + t8;
  const int bcol = (Lid % gx) * 128;
  const int brow = (Lid / gx) * 128;

  const int l = tid & 63, w = tid >> 6;   // 8 waves
  const int wr = w >> 2;                   // 0..1: M half (64 rows)
  const int wn = w & 3;                    // 0..3: N quarter (32 cols)
  const int r16 = l & 15, kg = l >> 4;
  const int swzl = (r16 & 7) * 8;          // read granule XOR ((row&7)*8)
  const int srow = l >> 3, sg = l & 7;     // staging: row-in-8-chunk, granule
  const int stg_off = (sg ^ srow) * 8;     // B source pre-swizzle

  const int kz = blockIdx.z * K;
  const unsigned short* Bg = B + (size_t)bcol * ldb + kz + stg_off;

  // B: 2 chunks of 8 rows per wave
#define STBK(buf, kt) do { \
    gl16(Bg + (size_t)((w * 2 + 0) * 8 + srow) * ldb + (size_t)(kt) * 64, Bs + (buf) * 8192 + (w * 2 + 0) * 512); \
    gl16(Bg + (size_t)((w * 2 + 1) * 8 + srow) * ldb + (size_t)(kt) * 64, Bs + (buf) * 8192 + (w * 2 + 1) * 512); \
  } while (0)

  // A: lane owns (row_local = w*16 + q*8 + srow, granule sg of 8 f32), q = 0..1
  unsigned long long abase[2];
  int dstA[2];
  #pragma unroll
  for (int q = 0; q < 2; q++) {
    int row_local = w * 16 + q * 8 + srow;
    int rowA = brow + row_local;
    if (rowA >= nvalid) rowA = nvalid - 1;
    abase[q] = (unsigned long long)(A + (size_t)rowA * lda + kz + sg * 8);
    dstA[q] = row_local * 64 + ((sg ^ srow) * 8);   // row_local&7 == srow
  }

  const unsigned short* Ard = As + (wr * 64 + r16) * 64;
  const unsigned short* Brd = Bs + (wn * 32 + r16) * 64;

  f32x4 acc[4][2];
  #pragma unroll
  for (int m = 0; m < 4; m++)
    #pragma unroll
    for (int nn = 0; nn < 2; nn++) { f32x4 z = {0.f, 0.f, 0.f, 0.f}; acc[m][nn] = z; }

  short8v af[4], bfr[2];
  f32x4 ar[2][2];

#define ALOAD(kt) { \
    _Pragma("unroll") for (int q = 0; q < 2; q++) { \
      unsigned long long aq = abase[q] + (unsigned long long)(kt) * 256; \
      asm volatile("global_load_dwordx4 %0, %1, off" : "=v"(ar[q][0]) : "v"(aq) : "memory"); \
      asm volatile("global_load_dwordx4 %0, %1, off offset:16" : "=v"(ar[q][1]) : "v"(aq) : "memory"); \
    } }
#define AWRITE(buf) { \
    _Pragma("unroll") for (int q = 0; q < 2; q++) { \
      unsigned int d0_, d1_, d2_, d3_; \
      asm("v_cvt_pk_bf16_f32 %0, %1, %2" : "=v"(d0_) : "v"(ar[q][0][0]), "v"(ar[q][0][1])); \
      asm("v_cvt_pk_bf16_f32 %0, %1, %2" : "=v"(d1_) : "v"(ar[q][0][2]), "v"(ar[q][0][3])); \
      asm("v_cvt_pk_bf16_f32 %0, %1, %2" : "=v"(d2_) : "v"(ar[q][1][0]), "v"(ar[q][1][1])); \
      asm("v_cvt_pk_bf16_f32 %0, %1, %2" : "=v"(d3_) : "v"(ar[q][1][2]), "v"(ar[q][1][3])); \
      uint4 pv_; pv_.x = d0_; pv_.y = d1_; pv_.z = d2_; pv_.w = d3_; \
      *(uint4*)(As + (buf) * 8192 + dstA[q]) = pv_; \
    } }
#define LDAB(c, kk) { \
    _Pragma("unroll") for (int i = 0; i < 4; i++) \
      af[i] = *(const short8v*)(Ard + (c) * 8192 + i * 1024 + (((kk) * 32 + kg * 8) ^ swzl)); \
    _Pragma("unroll") for (int nn = 0; nn < 2; nn++) \
      bfr[nn] = *(const short8v*)(Brd + (c) * 8192 + nn * 1024 + (((kk) * 32 + kg * 8) ^ swzl)); }
#define MFMA8() { \
    __builtin_amdgcn_s_setprio(1); \
    _Pragma("unroll") for (int i = 0; i < 4; i++) \
      _Pragma("unroll") for (int nn = 0; nn < 2; nn++) \
        acc[i][nn] = __builtin_amdgcn_mfma_f32_16x16x32_bf16(af[i], bfr[nn], acc[i][nn], 0, 0, 0); \
    __builtin_amdgcn_s_setprio(0); }

  const int nk = K >> 6;
  // prologue: tile 0
  ALOAD(0);
  STBK(0, 0);
  asm volatile("s_waitcnt vmcnt(2)" ::: "memory");
  __builtin_amdgcn_sched_barrier(0);
  AWRITE(0);
  asm volatile("s_waitcnt vmcnt(0) lgkmcnt(0)" ::: "memory");
  __builtin_amdgcn_s_barrier();
  __builtin_amdgcn_sched_barrier(0);

  for (int j = 0; j < nk; j++) {
    const int c = j & 1, nb = c ^ 1;
    const bool pf = (j + 1 < nk);
    // issue next tile (A f32 to regs, B gl16) before compute
    if (pf) { ALOAD(j + 1); STBK(nb, j + 1); }
    // compute tile j
    LDAB(c, 0);
    MFMA8();
    LDAB(c, 1);
    MFMA8();
    // retire A (full compute phase of slack), convert + write; drain all; swap
    if (pf) {
      asm volatile("s_waitcnt vmcnt(2)" ::: "memory");
      __builtin_amdgcn_sched_barrier(0);
      AWRITE(nb);
    }
    asm volatile("s_waitcnt vmcnt(0) lgkmcnt(0)" ::: "memory");
    __builtin_amdgcn_s_barrier();
    __builtin_amdgcn_sched_barrier(0);
  }
#undef STBK
#undef ALOAD
#undef AWRITE
#undef LDAB
#undef MFMA8

  // epilogue: raw fp16 partial. C/D map: col = lane&15, row = (lane>>4)*4 + reg
  #pragma unroll
  for (int m = 0; m < 4; m++) {
    const int row0 = brow + wr * 64 + m * 16 + kg * 4;
    #pragma unroll
    for (int nn = 0; nn < 2; nn++) {
      const int col = bcol + wn * 32 + nn * 16 + r16;
      if (col < N) {
        #pragma unroll
        for (int rr = 0; rr < 4; rr++) {
          const int row = row0 + rr;
          if (row < M)
            Cout[(size_t)blockIdx.z * M * ldc + (size_t)row * ldc + col] = (_Float16)(acc[m][nn][rr]);
        }
      }
    }
  }
}

// ========== fc1 split-K reduce: h = relu(P0+P1+P2+bias) -> bf16, fused BN partial sums ==========
__global__ __launch_bounds__(256) void fc1_reduce(const _Float16* __restrict__ P, const float* __restrict__ bias,
                                                  unsigned short* __restrict__ h, float* __restrict__ part,
                                                  int n, int mpad) {
  int b = blockIdx.x, tid = threadIdx.x;
  int c0 = tid * 4;
  float4 bsv = *(const float4*)(bias + c0);
  float s[4] = {0,0,0,0}, qq[4] = {0,0,0,0};
  int rbeg = b * 32;
  for (int r = rbeg; r < rbeg + 32; r++) {
    h4v a0 = *(const h4v*)(P + (size_t)r * 1024 + c0);
    h4v a1 = *(const h4v*)(P + ((size_t)mpad + r) * 1024 + c0);
    h4v a2 = *(const h4v*)(P + ((size_t)2 * mpad + r) * 1024 + c0);
    float v0 = fmaxf((float)a0[0] + (float)a1[0] + (float)a2[0] + bsv.x, 0.f);
    float v1 = fmaxf((float)a0[1] + (float)a1[1] + (float)a2[1] + bsv.y, 0.f);
    float v2 = fmaxf((float)a0[2] + (float)a1[2] + (float)a2[2] + bsv.z, 0.f);
    float v3 = fmaxf((float)a0[3] + (float)a1[3] + (float)a2[3] + bsv.w, 0.f);
    if (r < n) {
      s[0] += v0; qq[0] += v0 * v0;
      s[1] += v1; qq[1] += v1 * v1;
      s[2] += v2; qq[2] += v2 * v2;
      s[3] += v3; qq[3] += v3 * v3;
    }
    *(ushort4*)(h + (size_t)r * 1024 + c0) = make_ushort4(f2bf(v0), f2bf(v1), f2bf(v2), f2bf(v3));
  }
  float* pp = part + (size_t)b * 2048;
  #pragma unroll
  for (int k = 0; k < 4; k++) { pp[(c0 + k) * 2] = s[k]; pp[(c0 + k) * 2 + 1] = qq[k]; }
}

// ================= persistent fused bidirectional LSTM =================
__global__ __launch_bounds__(256, 1)
void lstm_persist(const unsigned short* __restrict__ whhc, const unsigned short* __restrict__ bcp,
                  const _Float16* __restrict__ G,
                  const int* __restrict__ gf, const int* __restrict__ gb, const int* __restrict__ sb,
                  unsigned short* __restrict__ hst,
                  unsigned short* __restrict__ lfeat, int* __restrict__ flags)
{
  __shared__ __align__(16) unsigned short Bsh[128 * 512];   // 128 KB resident whh tile
  const int tid = threadIdx.x;
  const int l = tid & 63, w = tid >> 6;
  const int b = blockIdx.x;
  const int grp = b & 15;          // (d, rg)
  const int c = b >> 4;            // 0..15 h-col block
  const int d = grp >> 3;
  const int rowbase = d * 512 + (grp & 7) * 64;
  const int r16 = l & 15, kg = l >> 4;
  const int swzl = (r16 & 7) * 8;
  const int hu0 = c * 32 + r16;

  const unsigned short* Bsrc = whhc + ((size_t)(d * 2048 + c * 128)) * 512;
  #pragma unroll
  for (int i = 0; i < 32; i++) {
    int rr = w * 32 + i;
    gl16(Bsrc + (size_t)rr * 512 + ((l * 8) ^ ((rr & 7) * 8)), Bsh + rr * 512);
  }
  asm volatile("s_waitcnt vmcnt(0)");
  __syncthreads();

  float creg[2][4];
  #pragma unroll
  for (int m = 0; m < 2; m++)
    #pragma unroll
    for (int rr = 0; rr < 4; rr++) creg[m][rr] = 0.f;

  const size_t stbase = (size_t)(((grp * 4 + w) * 16 + c) * 4 + (r16 >> 3)) * 128 + (size_t)kg * 32 + (r16 & 7);
  const size_t ldbase = ((size_t)(grp * 64 + w * 16) * 1024) + (size_t)l * 16;

  for (int t = 0; t < 32; t++) {
    ushort4 gv[2][4];
    int scv[4];
    #pragma unroll
    for (int rr = 0; rr < 4; rr++) {
      int row = rowbase + w * 16 + kg * 4 + rr;
      int sq = row & 511;
      int gi = d ? gb[sq * 32 + t] : gf[sq * 32 + t];
      const unsigned short* src = (gi >= 0)
          ? (const unsigned short*)G + ((size_t)gi * 4096 + (d << 11))
          : bcp + (d << 11);
      gv[0][rr] = *(const ushort4*)(src + hu0 * 4);
      gv[1][rr] = *(const ushort4*)(src + (hu0 + 16) * 4);
      scv[rr] = d ? sb[sq * 32 + t] : gi;
    }

    if (t > 0) {
      while (true) {
        int fv = 0x7fffffff;
        if (l < 16)
          fv = __hip_atomic_load(flags + ((grp * 16 + l) << 5), __ATOMIC_RELAXED, __HIP_MEMORY_SCOPE_AGENT);
        if (__all(fv >= t)) break;
        __builtin_amdgcn_s_sleep(1);
      }
    }
    asm volatile("" ::: "memory");

    const unsigned short* hp = hst + (size_t)(t & 1) * 524288;
    unsigned short* hn = hst + (size_t)((t + 1) & 1) * 524288;

    short8v av[16];
    {
      unsigned long long a64 = (unsigned long long)((const char*)hp + ldbase);
      #pragma unroll
      for (int kq = 0; kq < 4; kq++) {
        unsigned long long aq = a64 + (unsigned long long)kq * 4096;
        asm volatile("global_load_dwordx4 %0, %1, off offset:0 sc0 sc1"
                     : "=v"(av[kq * 4 + 0]) : "v"(aq) : "memory");
        asm volatile("global_load_dwordx4 %0, %1, off offset:1024 sc0 sc1"
                     : "=v"(av[kq * 4 + 1]) : "v"(aq) : "memory");
        asm volatile("global_load_dwordx4 %0, %1, off offset:2048 sc0 sc1"
                     : "=v"(av[kq * 4 + 2]) : "v"(aq) : "memory");
        asm volatile("global_load_dwordx4 %0, %1, off offset:3072 sc0 sc1"
                     : "=v"(av[kq * 4 + 3]) : "v"(aq) : "memory");
      }
    }
    asm volatile("s_waitcnt vmcnt(0)" ::: "memory");

    f32x4 acc[8];
    #pragma unroll
    for (int nn = 0; nn < 8; nn++) { f32x4 z = {0.f, 0.f, 0.f, 0.f}; acc[nn] = z; }

    #pragma unroll
    for (int kc = 0; kc < 8; kc++) {
      short8v bv[8][2];
      #pragma unroll
      for (int nn = 0; nn < 8; nn++)
        #pragma unroll
        for (int kk = 0; kk < 2; kk++)
          bv[nn][kk] = *(const short8v*)(Bsh + (nn * 16 + r16) * 512 + ((kc * 64 + kk * 32 + kg * 8) ^ swzl));
      #pragma unroll
      for (int kk = 0; kk < 2; kk++)
        #pragma unroll
        for (int nn = 0; nn < 8; nn++)
          acc[nn] = __builtin_amdgcn_mfma_f32_16x16x32_bf16(av[kc * 2 + kk], bv[nn][kk], acc[nn], 0, 0, 0);
    }

    unsigned long long ha = (unsigned long long)((char*)hn + stbase * 2);
    #pragma unroll
    for (int cgl = 0; cgl < 2; cgl++) {
      const int hu = hu0 + cgl * 16;
      #pragma unroll
      for (int reg = 0; reg < 4; reg++) {
        float g_i = acc[cgl * 4 + 0][reg] + fp16f(gv[cgl][reg].x);
        float g_f = acc[cgl * 4 + 1][reg] + fp16f(gv[cgl][reg].y);
        float g_g = acc[cgl * 4 + 2][reg] + fp16f(gv[cgl][reg].z);
        float g_o = acc[cgl * 4 + 3][reg] + fp16f(gv[cgl][reg].w);
        float si = 1.f / (1.f + __expf(-g_i));
        float sf = 1.f / (1.f + __expf(-g_f));
        float so = 1.f / (1.f + __expf(-g_o));
        float cn = sf * creg[cgl][reg] + si * tanhf(g_g);
        float hnv = so * tanhf(cn);
        creg[cgl][reg] = cn;
        unsigned int hb = f2bf(hnv);
        if (cgl == 0) {
          if (reg == 0) asm volatile("global_store_short %0, %1, off offset:0 sc0 sc1" :: "v"(ha), "v"(hb) : "memory");
          if (reg == 1) asm volatile("global_store_short %0, %1, off offset:16 sc0 sc1" :: "v"(ha), "v"(hb) : "memory");
          if (reg == 2) asm volatile("global_store_short %0, %1, off offset:32 sc0 sc1" :: "v"(ha), "v"(hb) : "memory");
          if (reg == 3) asm volatile("global_store_short %0, %1, off offset:48 sc0 sc1" :: "v"(ha), "v"(hb) : "memory");
        } else {
          if (reg == 0) asm volatile("global_store_short %0, %1, off offset:512 sc0 sc1" :: "v"(ha), "v"(hb) : "memory");
          if (reg == 1) asm volatile("global_store_short %0, %1, off offset:528 sc0 sc1" :: "v"(ha), "v"(hb) : "memory");
          if (reg == 2) asm volatile("global_store_short %0, %1, off offset:544 sc0 sc1" :: "v"(ha), "v"(hb) : "memory");
          if (reg == 3) asm volatile("global_store_short %0, %1, off offset:560 sc0 sc1" :: "v"(ha), "v"(hb) : "memory");
        }
        int sc = scv[reg];
        if (sc >= 0) lfeat[(size_t)sc * 1024 + d * 512 + hu] = f2bf(hnv);
      }
    }

    __syncthreads();
    if (t < 31 && tid == 0)
      __hip_atomic_store(flags + ((grp * 16 + c) << 5), t + 1, __ATOMIC_RELAXED, __HIP_MEMORY_SCOPE_AGENT);
  }
}

// ================= helpers =================
__global__ __launch_bounds__(256) void conv_bf16(const float* __restrict__ src, unsigned short* __restrict__ dst,
                                                 size_t nvalid, size_t total) {
  size_t stride = (size_t)gridDim.x * 2048;
  for (size_t i = ((size_t)blockIdx.x * 256 + threadIdx.x) * 8; i < total; i += stride) {
    unsigned short o[8];
    if (i + 8 <= nvalid) {
      float4 a = *(const float4*)(src + i);
      float4 b = *(const float4*)(src + i + 4);
      o[0] = f2bf(a.x); o[1] = f2bf(a.y); o[2] = f2bf(a.z); o[3] = f2bf(a.w);
      o[4] = f2bf(b.x); o[5] = f2bf(b.y); o[6] = f2bf(b.z); o[7] = f2bf(b.w);
    } else {
      #pragma unroll
      for (int j = 0; j < 8; j++) o[j] = (i + j < nvalid) ? f2bf(src[i + j]) : (unsigned short)0;
    }
    *(ushort4*)(dst + i) = make_ushort4(o[0], o[1], o[2], o[3]);
    *(ushort4*)(dst + i + 4) = make_ushort4(o[4], o[5], o[6], o[7]);
  }
}

__global__ __launch_bounds__(256) void bn_final(const float* __restrict__ part, const float* __restrict__ gamma,
                                                const float* __restrict__ beta, float* __restrict__ scale,
                                                float* __restrict__ shift, int M, int nb) {
  int c = blockIdx.x * 256 + threadIdx.x;
  float s = 0.f, q = 0.f;
  for (int b = 0; b < nb; b++) { s += part[(size_t)b * 2048 + c * 2]; q += part[(size_t)b * 2048 + c * 2 + 1]; }
  float mean = s / (float)M;
  float var = q / (float)M - mean * mean;
  float sc = gamma[c] * rsqrtf(var + 1e-5f);
  scale[c] = sc; shift[c] = beta[c] - mean * sc;
}

__global__ __launch_bounds__(256) void prep_tables(const int* __restrict__ seq_idx, const int* __restrict__ lengths,
                                                   int* __restrict__ gf, int* __restrict__ gb, int* __restrict__ sb) {
  int idx = blockIdx.x * 256 + threadIdx.x;
  if (idx < 512 * 32) {
    int s = idx >> 5, t = idx & 31;
    int len = lengths[s];
    gf[idx] = (t < len) ? seq_idx[idx] : -1;
    int rb = len - 1 - t;
    gb[idx] = seq_idx[(s << 5) + (rb < 0 ? 0 : rb)];
    sb[idx] = (t < len) ? seq_idx[(s << 5) + (len - 1 - t)] : -1;
  }
}

__global__ __launch_bounds__(256) void build_wih(const float* __restrict__ wf, const float* __restrict__ wb,
                                                 const float* __restrict__ bihf, const float* __restrict__ bhhf,
                                                 const float* __restrict__ bihb, const float* __restrict__ bhhb,
                                                 const float* __restrict__ scale, const float* __restrict__ shift,
                                                 unsigned short* __restrict__ wcdst, float* __restrict__ bc,
                                                 _Float16* __restrict__ bcp) {
  int orow = blockIdx.x * 4 + (threadIdx.x >> 6);
  int l = threadIdx.x & 63;
  int dir = orow >> 11, j = orow & 2047;
  int cc = j >> 6, jj = j & 63, g = jj >> 4, u = jj & 15;
  int srow = g * 512 + cc * 16 + u;
  const float* src = (dir ? wb : wf) + (size_t)srow * 1024;
  unsigned short* dst = wcdst + (size_t)orow * 1024;
  float sacc = 0.f;
  #pragma unroll
  for (int jv = 0; jv < 16; jv++) {
    int k = l + jv * 64;
    float v = src[k];
    sacc += shift[k] * v;
    dst[k] = f2bf(v * scale[k]);
  }
  #pragma unroll
  for (int o2 = 32; o2 > 0; o2 >>= 1) sacc += __shfl_down(sacc, o2);
  if (l == 0) {
    float bb = (dir ? (bihb[srow] + bhhb[srow]) : (bihf[srow] + bhhf[srow])) + sacc;
    bc[orow] = bb;
    int pc = (dir << 11) + (((cc << 4) + u) << 2) + g;
    bcp[pc] = (_Float16)bb;
  }
}

// whhc rows: orow = d*2048 + c*128 + L, L = cgl*64 + g*16 + u -> src row g*512 + (c*32 + cgl*16 + u)
__global__ __launch_bounds__(256) void build_whh(const float* __restrict__ wf, const float* __restrict__ wb,
                                                 unsigned short* __restrict__ o) {
  int cidx = blockIdx.x * 256 + threadIdx.x;
  if (cidx < 4096 * 64) {
    int orow = cidx >> 6, k0 = (cidx & 63) * 8;
    int dir = orow >> 11, j = orow & 2047;
    int cc = j >> 7, L = j & 127;
    int cgl = L >> 6, g = (L >> 4) & 3, u = L & 15;
    int hunit = cc * 32 + cgl * 16 + u;
    const float* src = (dir ? wb : wf) + (size_t)(g * 512 + hunit) * 512 + k0;
    unsigned short* dst = o + (size_t)orow * 512 + k0;
    float4 a = *(const float4*)(src);
    float4 bq = *(const float4*)(src + 4);
    dst[0] = f2bf(a.x); dst[1] = f2bf(a.y); dst[2] = f2bf(a.z); dst[3] = f2bf(a.w);
    dst[4] = f2bf(bq.x); dst[5] = f2bf(bq.y); dst[6] = f2bf(bq.z); dst[7] = f2bf(bq.w);
  }
}

extern "C" void kernel_launch(void* const* d_in, const int* in_sizes, int n_in,
                              void* d_out, int out_size, void* d_ws, size_t ws_size,
                              hipStream_t stream) {
  const float* x     = (const float*)d_in[0];
  const float* fc1w  = (const float*)d_in[1];
  const float* fc1b  = (const float*)d_in[2];
  const float* gamma = (const float*)d_in[3];
  const float* beta  = (const float*)d_in[4];
  const float* fc2w  = (const float*)d_in[5];
  const float* fc2b  = (const float*)d_in[6];
  const float* wihf  = (const float*)d_in[7];
  const float* whhf  = (const float*)d_in[8];
  const float* bihf  = (const float*)d_in[9];
  const float* bhhf  = (const float*)d_in[10];
  const float* wihb  = (const float*)d_in[11];
  const float* whhb  = (const float*)d_in[12];
  const float* bihb  = (const float*)d_in[13];
  const float* bhhb  = (const float*)d_in[14];
  const int* seq_idx = (const int*)d_in[15];
  const int* lengths = (const int*)d_in[16];
  float* out = (float*)d_out;

  const int n = in_sizes[0] / 13824;           // 9121
  const int mt = (n + 255) / 256;              // 36 M-tiles of 256
  const int mpad = mt * 256;                   // 9216
  const int mt128 = mpad / 128;                // 72

  char* ws = (char*)d_ws;
  size_t off = 0;
  auto alloc = [&](size_t bytes) -> void* {
    void* p = ws + off; off += (bytes + 255) & ~(size_t)255; return p;
  };
  unsigned short* w1_h = (unsigned short*)alloc((size_t)1024 * 13824 * 2);
  unsigned short* w2_h = (unsigned short*)alloc((size_t)4864 * 1024 * 2);
  unsigned short* h    = (unsigned short*)alloc((size_t)mpad * 1024 * 2);
  _Float16*       G    = (_Float16*)alloc((size_t)mpad * 4096 * 2);  // also aliased as split-K partials
  unsigned short* wihc = (unsigned short*)alloc((size_t)4096 * 1024 * 2);
  unsigned short* whhc = (unsigned short*)alloc((size_t)4096 * 512 * 2);
  float* bias_c = (float*)alloc(4096 * 4);
  _Float16* bias_p = (_Float16*)alloc(4096 * 2);
  unsigned short* lfeat  = (unsigned short*)alloc((size_t)mpad * 1024 * 2);
  unsigned short* hstate = (unsigned short*)alloc((size_t)2 * 1024 * 512 * 2);
  float* part   = (float*)alloc((size_t)(mpad / 32) * 2048 * 4);
  float* scale  = (float*)alloc(1024 * 4);
  float* shift  = (float*)alloc(1024 * 4);
  int* gf  = (int*)alloc(16384 * 4);
  int* gb  = (int*)alloc(16384 * 4);
  int* sb  = (int*)alloc(16384 * 4);
  int* flags = (int*)alloc(256 * 32 * 4);

  _Float16* P16 = (_Float16*)G;   // fc1 split-K fp16 partials [3][mpad][1024] (56.6 MB <= G size 75.5 MB)

  dim3 blk(256);
  dim3 blk5(512);

  conv_bf16<<<1024, blk, 0, stream>>>(fc1w, w1_h, (size_t)1024 * 13824, (size_t)1024 * 13824);
  conv_bf16<<<256, blk, 0, stream>>>(fc2w, w2_h, (size_t)4787 * 1024, (size_t)4864 * 1024);
  build_whh<<<1024, blk, 0, stream>>>(whhf, whhb, whhc);
  prep_tables<<<64, blk, 0, stream>>>(seq_idx, lengths, gf, gb, sb);
  hipMemsetAsync(hstate, 0, (size_t)2 * 1024 * 512 * 2, stream);
  hipMemsetAsync(flags, 0, 256 * 32 * 4, stream);

  // fc1 split-K with fused f32->bf16 A conversion: P16[z] = x @ w1^T (K chunk z), z in {0,1,2}
  // 128x128 tiles, 2 WGs/CU (occupancy lever)
  gemm128fA<<<dim3(8, mt128, 3), blk5, 0, stream>>>(
      x, w1_h, P16, mpad, 1024, 4608, 13824, 13824, 1024, n);

  // reduce + bias + relu -> h bf16, fused BN partial sums
  fc1_reduce<<<mpad / 32, blk, 0, stream>>>(P16, fc1b, h, part, n, mpad);
  bn_final<<<4, blk, 0, stream>>>(part, gamma, beta, scale, shift, n, mpad / 32);
  build_wih<<<1024, blk, 0, stream>>>(wihf, wihb, bihf, bhhf, bihb, bhhb, scale, shift, wihc, bias_c, bias_p);

  // G = feats @ wih_c^T + bias_c -> fp16, unit-packed (BN folded; overwrites P16 after it's consumed)
  gemm256<3><<<dim3(16, mt), blk5, 0, stream>>>(
      h, wihc, G, n, 4096, 1024, 1024, 1024, 4096, bias_c);

  // fused persistent bidirectional LSTM (32 steps)
  lstm_persist<<<256, blk, 0, stream>>>(whhc, (const unsigned short*)bias_p, G, gf, gb, sb,
                                        hstate, lfeat, flags);

  // fc2: out = lstm_feats @ fc2w^T + b
  gemm256<0><<<dim3(19, mt), blk5, 0, stream>>>(
      lfeat, w2_h, out, n, 4787, 1024, 1024, 1024, 4787, fc2b);
}

// Round 9
// 1089.938 us; speedup vs baseline: 1.0381x; 1.0381x over previous
//
#include <hip/hip_runtime.h>

typedef short short8v __attribute__((ext_vector_type(8)));
typedef float f32x4 __attribute__((ext_vector_type(4)));
typedef _Float16 h4v __attribute__((ext_vector_type(4)));

__device__ __forceinline__ unsigned short f2bf(float f){
  unsigned int u = __float_as_uint(f);
  u += 0x7fffu + ((u >> 16) & 1u);
  return (unsigned short)(u >> 16);
}
__device__ __forceinline__ float bf2f(unsigned short h){
  return __uint_as_float(((unsigned int)h) << 16);
}
union H2F { unsigned short u; _Float16 h; };
__device__ __forceinline__ float fp16f(unsigned short b){ H2F t; t.u = b; return (float)t.h; }

typedef __attribute__((address_space(1))) const unsigned int gu32;
typedef __attribute__((address_space(3))) unsigned int lu32;
__device__ __forceinline__ void gl16(const void* g, void* l){
  __builtin_amdgcn_global_load_lds((gu32*)g, (lu32*)l, 16, 0, 0);
}

// ========== 256x256 GEMM: C = A @ B^T, bf16 in; 4-phase staggered prefetch (proven schedule) ==========
// EPI 0: +bias -> f32 (fc2) | EPI 3: +bias -> fp16 unit-packed (G)
template<int EPI>
__global__ __launch_bounds__(512, 2)
void gemm256(const unsigned short* __restrict__ A, const unsigned short* __restrict__ B,
             void* __restrict__ Cout, int M, int N, int K, int lda, int ldb, int ldc,
             const float* __restrict__ bias)
{
  __shared__ __align__(16) unsigned short As[2 * 2 * 256 * 32];   // 64 KB
  __shared__ __align__(16) unsigned short Bs[2 * 2 * 256 * 32];   // 64 KB

  const int tid = threadIdx.x;
  const int gx = gridDim.x;
  const int nwg = gx * gridDim.y;
  int dd = blockIdx.y * gx + blockIdx.x;
  int q8 = nwg >> 3, r8 = nwg & 7, xc = dd & 7, t8 = dd >> 3;
  int Lid = (xc < r8 ? xc * (q8 + 1) : r8 * (q8 + 1) + (xc - r8) * q8) + t8;
  const int bcol = (Lid % gx) * 256;
  const int brow = (Lid / gx) * 256;

  const int l = tid & 63, w = tid >> 6;
  const int wr = w >> 2;                 // M half (0..1)
  const int wn = w & 3;                  // N quarter (0..3)
  const int r16 = l & 15, kg = l >> 4;
  const int swz = (r16 >> 1) & 3;
  const int srow4 = l >> 2, sblk = l & 3;
  const int scol = (sblk ^ ((l >> 3) & 3)) * 8;

  const int kz = blockIdx.z * K;
  const unsigned short* Ag = A + (size_t)(brow + w * 32 + srow4) * lda + kz + scol;
  const unsigned short* Bg = B + (size_t)(bcol + w * 32 + srow4) * ldb + kz + scol;
  unsigned short* Asd = As + w * 1024;
  unsigned short* Bsd = Bs + w * 1024;

#define STA(buf, kh, kt) do { \
    gl16(Ag + (size_t)(kt) * 64 + (kh) * 32, Asd + (buf) * 16384 + (kh) * 8192); \
    gl16(Ag + (size_t)(kt) * 64 + (kh) * 32 + (size_t)16 * lda, Asd + (buf) * 16384 + (kh) * 8192 + 512); \
  } while (0)
#define STB(buf, kh, kt) do { \
    gl16(Bg + (size_t)(kt) * 64 + (kh) * 32, Bsd + (buf) * 16384 + (kh) * 8192); \
    gl16(Bg + (size_t)(kt) * 64 + (kh) * 32 + (size_t)16 * ldb, Bsd + (buf) * 16384 + (kh) * 8192 + 512); \
  } while (0)

  const unsigned short* Ard = As + (wr * 128 + r16) * 32 + ((kg ^ swz) * 8);
  const unsigned short* Brd = Bs + (wn * 64 + r16) * 32 + ((kg ^ swz) * 8);

  f32x4 acc[8][4];
  #pragma unroll
  for (int m = 0; m < 8; m++)
    #pragma unroll
    for (int nn = 0; nn < 4; nn++) { f32x4 z = {0.f, 0.f, 0.f, 0.f}; acc[m][nn] = z; }

  short8v af[4], bfr[4];

#define LDA4(c, kk, mq) { \
    _Pragma("unroll") for (int i = 0; i < 4; i++) \
      af[i] = *(const short8v*)(Ard + (c) * 16384 + (kk) * 8192 + ((mq) * 4 + i) * 512); }
#define LDB4(c, kk) { \
    _Pragma("unroll") for (int nn = 0; nn < 4; nn++) \
      bfr[nn] = *(const short8v*)(Brd + (c) * 16384 + (kk) * 8192 + nn * 512); }
#define MFMAQ(mq) { \
    __builtin_amdgcn_s_setprio(1); \
    _Pragma("unroll") for (int i = 0; i < 4; i++) { \
      _Pragma("unroll") for (int nn = 0; nn < 4; nn++) \
        acc[(mq) * 4 + i][nn] = __builtin_amdgcn_mfma_f32_16x16x32_bf16(af[i], bfr[nn], acc[(mq) * 4 + i][nn], 0, 0, 0); \
    } \
    __builtin_amdgcn_s_setprio(0); }

  const int nk = K >> 6;
  STA(0, 0, 0); STB(0, 0, 0); STA(0, 1, 0); STB(0, 1, 0);
  asm volatile("s_waitcnt vmcnt(4)" ::: "memory");
  __builtin_amdgcn_s_barrier();
  __builtin_amdgcn_sched_barrier(0);

  for (int j = 0; j < nk; j++) {
    const int c = j & 1, nb = c ^ 1;
    const bool pf = (j + 1 < nk);
    // phase 1
    LDB4(c, 0); LDA4(c, 0, 0);
    if (pf) STA(nb, 0, j + 1);
    __builtin_amdgcn_s_barrier();
    MFMAQ(0);
    __builtin_amdgcn_s_barrier();
    // phase 2
    LDA4(c, 0, 1);
    if (pf) STB(nb, 0, j + 1);
    __builtin_amdgcn_s_barrier();
    MFMAQ(1);
    if (pf) asm volatile("s_waitcnt vmcnt(4)" ::: "memory");
    else    asm volatile("s_waitcnt vmcnt(0)" ::: "memory");
    __builtin_amdgcn_s_barrier();
    __builtin_amdgcn_sched_barrier(0);
    // phase 3
    LDB4(c, 1); LDA4(c, 1, 0);
    if (pf) STA(nb, 1, j + 1);
    __builtin_amdgcn_s_barrier();
    MFMAQ(0);
    __builtin_amdgcn_s_barrier();
    // phase 4
    LDA4(c, 1, 1);
    if (pf) STB(nb, 1, j + 1);
    __builtin_amdgcn_s_barrier();
    MFMAQ(1);
    if (pf) asm volatile("s_waitcnt vmcnt(4)" ::: "memory");
    __builtin_amdgcn_s_barrier();
    __builtin_amdgcn_sched_barrier(0);
  }
#undef STA
#undef STB
#undef LDA4
#undef LDB4
#undef MFMAQ

  // C/D map: col = lane&15, row = (lane>>4)*4 + reg
  #pragma unroll
  for (int m = 0; m < 8; m++) {
    const int row0 = brow + wr * 128 + m * 16 + kg * 4;
    #pragma unroll
    for (int nn = 0; nn < 4; nn++) {
      const int col = bcol + wn * 64 + nn * 16 + r16;
      if (col < N) {
        const float bv = bias[col];
        #pragma unroll
        for (int rr = 0; rr < 4; rr++) {
          const int row = row0 + rr;
          if (row < M) {
            float val = acc[m][nn][rr] + bv;
            if (EPI == 3) {
              int dL = col >> 11, rc = col & 2047;
              int cg = rc >> 6, g = (rc >> 4) & 3, u = rc & 15;
              int pc = (dL << 11) + (((cg << 4) + u) << 2) + g;
              ((_Float16*)Cout)[(size_t)row * ldc + pc] = (_Float16)val;
            } else {
              ((float*)Cout)[(size_t)row * ldc + col] = val;
            }
          }
        }
      }
    }
  }
}

// ========== fc1 GEMM with fused f32->bf16 A conversion (replaces conv_x + gemm<5>) ==========
// A is raw f32 (x). Lane owns one (row, 8-consecutive-f32 granule) per q: 2x dwordx4 ->
// 4x v_cvt_pk_bf16_f32 -> ONE ds_write_b128 at the swizzled slot (<=2-way bank aliasing).
// Schedule: A loads ph1 (oldest), both B gl16 pieces ph2, vmcnt(4)+AWRITE ph3 (A slack = 2 phases),
// vmcnt(0)+lgkmcnt(0) at ph4 end drains B staged 2 phases earlier.
__global__ __launch_bounds__(512, 2)
void gemm256fA(const float* __restrict__ A, const unsigned short* __restrict__ B,
               _Float16* __restrict__ Cout, int M, int N, int K, int lda, int ldb, int ldc,
               int nvalid)
{
  __shared__ __align__(16) unsigned short As[2 * 2 * 256 * 32];   // 64 KB
  __shared__ __align__(16) unsigned short Bs[2 * 2 * 256 * 32];   // 64 KB

  const int tid = threadIdx.x;
  const int gx = gridDim.x;
  const int nwg = gx * gridDim.y;
  int dd = blockIdx.y * gx + blockIdx.x;
  int q8 = nwg >> 3, r8 = nwg & 7, xc = dd & 7, t8 = dd >> 3;
  int Lid = (xc < r8 ? xc * (q8 + 1) : r8 * (q8 + 1) + (xc - r8) * q8) + t8;
  const int bcol = (Lid % gx) * 256;
  const int brow = (Lid / gx) * 256;

  const int l = tid & 63, w = tid >> 6;
  const int wr = w >> 2;
  const int wn = w & 3;
  const int r16 = l & 15, kg = l >> 4;
  const int swz = (r16 >> 1) & 3;
  const int srow4 = l >> 2, sblk = l & 3;
  const int scol = (sblk ^ ((l >> 3) & 3)) * 8;

  const int kz = blockIdx.z * K;
  const unsigned short* Bg = B + (size_t)(bcol + w * 32 + srow4) * ldb + kz + scol;
  unsigned short* Bsd = Bs + w * 1024;

#define STB(buf, kh, kt) do { \
    gl16(Bg + (size_t)(kt) * 64 + (kh) * 32, Bsd + (buf) * 16384 + (kh) * 8192); \
    gl16(Bg + (size_t)(kt) * 64 + (kh) * 32 + (size_t)16 * ldb, Bsd + (buf) * 16384 + (kh) * 8192 + 512); \
  } while (0)

  // --- A reg-staging geometry: lane -> (row, 8-f32 granule), q = 0..3 ---
  const int rsel8 = l >> 3;         // 0..7 row within 8-row group
  const int g8 = l & 7;             // granule of 8 consecutive f32 within the 64-k tile
  unsigned long long abase[4];
  int dstA[4];
  #pragma unroll
  for (int q = 0; q < 4; q++) {
    int row_local = w * 32 + q * 8 + rsel8;
    int rowA = brow + row_local;
    if (rowA >= nvalid) rowA = nvalid - 1;
    abase[q] = (unsigned long long)(A + (size_t)rowA * lda + kz + g8 * 8);
    int kh = g8 >> 2, gA = g8 & 3, swi = (row_local >> 1) & 3;
    dstA[q] = kh * 8192 + row_local * 32 + ((gA ^ swi) * 8);
  }

  const unsigned short* Ard = As + (wr * 128 + r16) * 32 + ((kg ^ swz) * 8);
  const unsigned short* Brd = Bs + (wn * 64 + r16) * 32 + ((kg ^ swz) * 8);

  f32x4 acc[8][4];
  #pragma unroll
  for (int m = 0; m < 8; m++)
    #pragma unroll
    for (int nn = 0; nn < 4; nn++) { f32x4 z = {0.f, 0.f, 0.f, 0.f}; acc[m][nn] = z; }

  short8v af[4], bfr[4];
  f32x4 ar[4][2];

#define ALOAD(kt) { \
    _Pragma("unroll") for (int q = 0; q < 4; q++) { \
      unsigned long long aq = abase[q] + (unsigned long long)(kt) * 256; \
      asm volatile("global_load_dwordx4 %0, %1, off" : "=v"(ar[q][0]) : "v"(aq) : "memory"); \
      asm volatile("global_load_dwordx4 %0, %1, off offset:16" : "=v"(ar[q][1]) : "v"(aq) : "memory"); \
    } }
#define AWRITE(buf) { \
    _Pragma("unroll") for (int q = 0; q < 4; q++) { \
      unsigned int d0_, d1_, d2_, d3_; \
      asm("v_cvt_pk_bf16_f32 %0, %1, %2" : "=v"(d0_) : "v"(ar[q][0][0]), "v"(ar[q][0][1])); \
      asm("v_cvt_pk_bf16_f32 %0, %1, %2" : "=v"(d1_) : "v"(ar[q][0][2]), "v"(ar[q][0][3])); \
      asm("v_cvt_pk_bf16_f32 %0, %1, %2" : "=v"(d2_) : "v"(ar[q][1][0]), "v"(ar[q][1][1])); \
      asm("v_cvt_pk_bf16_f32 %0, %1, %2" : "=v"(d3_) : "v"(ar[q][1][2]), "v"(ar[q][1][3])); \
      uint4 pv_; pv_.x = d0_; pv_.y = d1_; pv_.z = d2_; pv_.w = d3_; \
      *(uint4*)(As + (buf) * 16384 + dstA[q]) = pv_; \
    } }

  const int nk = K >> 6;
  // prologue: A tile0 (reg) + B tile0 (gl16, both pieces)
  ALOAD(0);
  STB(0, 0, 0); STB(0, 1, 0);
  asm volatile("s_waitcnt vmcnt(4)" ::: "memory");   // retire A loads (4 B gl16 remain)
  __builtin_amdgcn_sched_barrier(0);
  AWRITE(0);
  asm volatile("s_waitcnt vmcnt(0) lgkmcnt(0)" ::: "memory");
  __builtin_amdgcn_s_barrier();
  __builtin_amdgcn_sched_barrier(0);

#define LDA4(c, kk, mq) { \
    _Pragma("unroll") for (int i = 0; i < 4; i++) \
      af[i] = *(const short8v*)(Ard + (c) * 16384 + (kk) * 8192 + ((mq) * 4 + i) * 512); }
#define LDB4(c, kk) { \
    _Pragma("unroll") for (int nn = 0; nn < 4; nn++) \
      bfr[nn] = *(const short8v*)(Brd + (c) * 16384 + (kk) * 8192 + nn * 512); }
#define MFMAQ(mq) { \
    __builtin_amdgcn_s_setprio(1); \
    _Pragma("unroll") for (int i = 0; i < 4; i++) { \
      _Pragma("unroll") for (int nn = 0; nn < 4; nn++) \
        acc[(mq) * 4 + i][nn] = __builtin_amdgcn_mfma_f32_16x16x32_bf16(af[i], bfr[nn], acc[(mq) * 4 + i][nn], 0, 0, 0); \
    } \
    __builtin_amdgcn_s_setprio(0); }

  for (int j = 0; j < nk; j++) {
    const int c = j & 1, nb = c ^ 1;
    const bool pf = (j + 1 < nk);
    // phase 1: issue A loads for j+1 (oldest VMEM, 8 ops)
    LDB4(c, 0); LDA4(c, 0, 0);
    if (pf) ALOAD(j + 1);
    __builtin_amdgcn_s_barrier();
    MFMAQ(0);
    __builtin_amdgcn_s_barrier();
    // phase 2: stage BOTH B pieces for j+1 (4 gl16)
    LDA4(c, 0, 1);
    if (pf) { STB(nb, 0, j + 1); STB(nb, 1, j + 1); }
    __builtin_amdgcn_s_barrier();
    MFMAQ(1);
    __builtin_amdgcn_s_barrier();
    __builtin_amdgcn_sched_barrier(0);
    // phase 3: retire A loads (2 phases of slack), convert + b128 write
    LDB4(c, 1); LDA4(c, 1, 0);
    if (pf) {
      asm volatile("s_waitcnt vmcnt(4)" ::: "memory");
      __builtin_amdgcn_sched_barrier(0);
      AWRITE(nb);
    }
    __builtin_amdgcn_s_barrier();
    MFMAQ(0);
    __builtin_amdgcn_s_barrier();
    // phase 4: drain B (staged 2 phases ago) + ds_writes before the buffer-swap barrier
    LDA4(c, 1, 1);
    __builtin_amdgcn_s_barrier();
    MFMAQ(1);
    asm volatile("s_waitcnt vmcnt(0) lgkmcnt(0)" ::: "memory");
    __builtin_amdgcn_s_barrier();
    __builtin_amdgcn_sched_barrier(0);
  }
#undef STB
#undef ALOAD
#undef AWRITE
#undef LDA4
#undef LDB4
#undef MFMAQ

  // epilogue: raw fp16 partial
  #pragma unroll
  for (int m = 0; m < 8; m++) {
    const int row0 = brow + wr * 128 + m * 16 + kg * 4;
    #pragma unroll
    for (int nn = 0; nn < 4; nn++) {
      const int col = bcol + wn * 64 + nn * 16 + r16;
      if (col < N) {
        #pragma unroll
        for (int rr = 0; rr < 4; rr++) {
          const int row = row0 + rr;
          if (row < M)
            Cout[(size_t)blockIdx.z * M * ldc + (size_t)row * ldc + col] = (_Float16)(acc[m][nn][rr]);
        }
      }
    }
  }
}

// ========== fc1 split-K reduce: h = relu(P0+P1+P2+bias) -> bf16, fused BN partial sums ==========
__global__ __launch_bounds__(256) void fc1_reduce(const _Float16* __restrict__ P, const float* __restrict__ bias,
                                                  unsigned short* __restrict__ h, float* __restrict__ part,
                                                  int n, int mpad) {
  int b = blockIdx.x, tid = threadIdx.x;
  int c0 = tid * 4;
  float4 bsv = *(const float4*)(bias + c0);
  float s[4] = {0,0,0,0}, qq[4] = {0,0,0,0};
  int rbeg = b * 32;
  for (int r = rbeg; r < rbeg + 32; r++) {
    h4v a0 = *(const h4v*)(P + (size_t)r * 1024 + c0);
    h4v a1 = *(const h4v*)(P + ((size_t)mpad + r) * 1024 + c0);
    h4v a2 = *(const h4v*)(P + ((size_t)2 * mpad + r) * 1024 + c0);
    float v0 = fmaxf((float)a0[0] + (float)a1[0] + (float)a2[0] + bsv.x, 0.f);
    float v1 = fmaxf((float)a0[1] + (float)a1[1] + (float)a2[1] + bsv.y, 0.f);
    float v2 = fmaxf((float)a0[2] + (float)a1[2] + (float)a2[2] + bsv.z, 0.f);
    float v3 = fmaxf((float)a0[3] + (float)a1[3] + (float)a2[3] + bsv.w, 0.f);
    if (r < n) {
      s[0] += v0; qq[0] += v0 * v0;
      s[1] += v1; qq[1] += v1 * v1;
      s[2] += v2; qq[2] += v2 * v2;
      s[3] += v3; qq[3] += v3 * v3;
    }
    *(ushort4*)(h + (size_t)r * 1024 + c0) = make_ushort4(f2bf(v0), f2bf(v1), f2bf(v2), f2bf(v3));
  }
  float* pp = part + (size_t)b * 2048;
  #pragma unroll
  for (int k = 0; k < 4; k++) { pp[(c0 + k) * 2] = s[k]; pp[(c0 + k) * 2 + 1] = qq[k]; }
}

// ================= persistent fused bidirectional LSTM =================
__global__ __launch_bounds__(256, 1)
void lstm_persist(const unsigned short* __restrict__ whhc, const unsigned short* __restrict__ bcp,
                  const _Float16* __restrict__ G,
                  const int* __restrict__ gf, const int* __restrict__ gb, const int* __restrict__ sb,
                  unsigned short* __restrict__ hst,
                  unsigned short* __restrict__ lfeat, int* __restrict__ flags)
{
  __shared__ __align__(16) unsigned short Bsh[128 * 512];   // 128 KB resident whh tile
  const int tid = threadIdx.x;
  const int l = tid & 63, w = tid >> 6;
  const int b = blockIdx.x;
  const int grp = b & 15;          // (d, rg)
  const int c = b >> 4;            // 0..15 h-col block
  const int d = grp >> 3;
  const int rowbase = d * 512 + (grp & 7) * 64;
  const int r16 = l & 15, kg = l >> 4;
  const int swzl = (r16 & 7) * 8;
  const int hu0 = c * 32 + r16;

  const unsigned short* Bsrc = whhc + ((size_t)(d * 2048 + c * 128)) * 512;
  #pragma unroll
  for (int i = 0; i < 32; i++) {
    int rr = w * 32 + i;
    gl16(Bsrc + (size_t)rr * 512 + ((l * 8) ^ ((rr & 7) * 8)), Bsh + rr * 512);
  }
  asm volatile("s_waitcnt vmcnt(0)");
  __syncthreads();

  float creg[2][4];
  #pragma unroll
  for (int m = 0; m < 2; m++)
    #pragma unroll
    for (int rr = 0; rr < 4; rr++) creg[m][rr] = 0.f;

  const size_t stbase = (size_t)(((grp * 4 + w) * 16 + c) * 4 + (r16 >> 3)) * 128 + (size_t)kg * 32 + (r16 & 7);
  const size_t ldbase = ((size_t)(grp * 64 + w * 16) * 1024) + (size_t)l * 16;

  for (int t = 0; t < 32; t++) {
    ushort4 gv[2][4];
    int scv[4];
    #pragma unroll
    for (int rr = 0; rr < 4; rr++) {
      int row = rowbase + w * 16 + kg * 4 + rr;
      int sq = row & 511;
      int gi = d ? gb[sq * 32 + t] : gf[sq * 32 + t];
      const unsigned short* src = (gi >= 0)
          ? (const unsigned short*)G + ((size_t)gi * 4096 + (d << 11))
          : bcp + (d << 11);
      gv[0][rr] = *(const ushort4*)(src + hu0 * 4);
      gv[1][rr] = *(const ushort4*)(src + (hu0 + 16) * 4);
      scv[rr] = d ? sb[sq * 32 + t] : gi;
    }

    if (t > 0) {
      while (true) {
        int fv = 0x7fffffff;
        if (l < 16)
          fv = __hip_atomic_load(flags + ((grp * 16 + l) << 5), __ATOMIC_RELAXED, __HIP_MEMORY_SCOPE_AGENT);
        if (__all(fv >= t)) break;
        __builtin_amdgcn_s_sleep(1);
      }
    }
    asm volatile("" ::: "memory");

    const unsigned short* hp = hst + (size_t)(t & 1) * 524288;
    unsigned short* hn = hst + (size_t)((t + 1) & 1) * 524288;

    short8v av[16];
    {
      unsigned long long a64 = (unsigned long long)((const char*)hp + ldbase);
      #pragma unroll
      for (int kq = 0; kq < 4; kq++) {
        unsigned long long aq = a64 + (unsigned long long)kq * 4096;
        asm volatile("global_load_dwordx4 %0, %1, off offset:0 sc0 sc1"
                     : "=v"(av[kq * 4 + 0]) : "v"(aq) : "memory");
        asm volatile("global_load_dwordx4 %0, %1, off offset:1024 sc0 sc1"
                     : "=v"(av[kq * 4 + 1]) : "v"(aq) : "memory");
        asm volatile("global_load_dwordx4 %0, %1, off offset:2048 sc0 sc1"
                     : "=v"(av[kq * 4 + 2]) : "v"(aq) : "memory");
        asm volatile("global_load_dwordx4 %0, %1, off offset:3072 sc0 sc1"
                     : "=v"(av[kq * 4 + 3]) : "v"(aq) : "memory");
      }
    }
    asm volatile("s_waitcnt vmcnt(0)" ::: "memory");

    f32x4 acc[8];
    #pragma unroll
    for (int nn = 0; nn < 8; nn++) { f32x4 z = {0.f, 0.f, 0.f, 0.f}; acc[nn] = z; }

    #pragma unroll
    for (int kc = 0; kc < 8; kc++) {
      short8v bv[8][2];
      #pragma unroll
      for (int nn = 0; nn < 8; nn++)
        #pragma unroll
        for (int kk = 0; kk < 2; kk++)
          bv[nn][kk] = *(const short8v*)(Bsh + (nn * 16 + r16) * 512 + ((kc * 64 + kk * 32 + kg * 8) ^ swzl));
      #pragma unroll
      for (int kk = 0; kk < 2; kk++)
        #pragma unroll
        for (int nn = 0; nn < 8; nn++)
          acc[nn] = __builtin_amdgcn_mfma_f32_16x16x32_bf16(av[kc * 2 + kk], bv[nn][kk], acc[nn], 0, 0, 0);
    }

    unsigned long long ha = (unsigned long long)((char*)hn + stbase * 2);
    #pragma unroll
    for (int cgl = 0; cgl < 2; cgl++) {
      const int hu = hu0 + cgl * 16;
      #pragma unroll
      for (int reg = 0; reg < 4; reg++) {
        float g_i = acc[cgl * 4 + 0][reg] + fp16f(gv[cgl][reg].x);
        float g_f = acc[cgl * 4 + 1][reg] + fp16f(gv[cgl][reg].y);
        float g_g = acc[cgl * 4 + 2][reg] + fp16f(gv[cgl][reg].z);
        float g_o = acc[cgl * 4 + 3][reg] + fp16f(gv[cgl][reg].w);
        float si = 1.f / (1.f + __expf(-g_i));
        float sf = 1.f / (1.f + __expf(-g_f));
        float so = 1.f / (1.f + __expf(-g_o));
        float cn = sf * creg[cgl][reg] + si * tanhf(g_g);
        float hnv = so * tanhf(cn);
        creg[cgl][reg] = cn;
        unsigned int hb = f2bf(hnv);
        if (cgl == 0) {
          if (reg == 0) asm volatile("global_store_short %0, %1, off offset:0 sc0 sc1" :: "v"(ha), "v"(hb) : "memory");
          if (reg == 1) asm volatile("global_store_short %0, %1, off offset:16 sc0 sc1" :: "v"(ha), "v"(hb) : "memory");
          if (reg == 2) asm volatile("global_store_short %0, %1, off offset:32 sc0 sc1" :: "v"(ha), "v"(hb) : "memory");
          if (reg == 3) asm volatile("global_store_short %0, %1, off offset:48 sc0 sc1" :: "v"(ha), "v"(hb) : "memory");
        } else {
          if (reg == 0) asm volatile("global_store_short %0, %1, off offset:512 sc0 sc1" :: "v"(ha), "v"(hb) : "memory");
          if (reg == 1) asm volatile("global_store_short %0, %1, off offset:528 sc0 sc1" :: "v"(ha), "v"(hb) : "memory");
          if (reg == 2) asm volatile("global_store_short %0, %1, off offset:544 sc0 sc1" :: "v"(ha), "v"(hb) : "memory");
          if (reg == 3) asm volatile("global_store_short %0, %1, off offset:560 sc0 sc1" :: "v"(ha), "v"(hb) : "memory");
        }
        int sc = scv[reg];
        if (sc >= 0) lfeat[(size_t)sc * 1024 + d * 512 + hu] = f2bf(hnv);
      }
    }

    __syncthreads();
    if (t < 31 && tid == 0)
      __hip_atomic_store(flags + ((grp * 16 + c) << 5), t + 1, __ATOMIC_RELAXED, __HIP_MEMORY_SCOPE_AGENT);
  }
}

// ================= helpers =================
__global__ __launch_bounds__(256) void conv_bf16(const float* __restrict__ src, unsigned short* __restrict__ dst,
                                                 size_t nvalid, size_t total) {
  size_t stride = (size_t)gridDim.x * 2048;
  for (size_t i = ((size_t)blockIdx.x * 256 + threadIdx.x) * 8; i < total; i += stride) {
    unsigned short o[8];
    if (i + 8 <= nvalid) {
      float4 a = *(const float4*)(src + i);
      float4 b = *(const float4*)(src + i + 4);
      o[0] = f2bf(a.x); o[1] = f2bf(a.y); o[2] = f2bf(a.z); o[3] = f2bf(a.w);
      o[4] = f2bf(b.x); o[5] = f2bf(b.y); o[6] = f2bf(b.z); o[7] = f2bf(b.w);
    } else {
      #pragma unroll
      for (int j = 0; j < 8; j++) o[j] = (i + j < nvalid) ? f2bf(src[i + j]) : (unsigned short)0;
    }
    *(ushort4*)(dst + i) = make_ushort4(o[0], o[1], o[2], o[3]);
    *(ushort4*)(dst + i + 4) = make_ushort4(o[4], o[5], o[6], o[7]);
  }
}

__global__ __launch_bounds__(256) void bn_final(const float* __restrict__ part, const float* __restrict__ gamma,
                                                const float* __restrict__ beta, float* __restrict__ scale,
                                                float* __restrict__ shift, int M, int nb) {
  int c = blockIdx.x * 256 + threadIdx.x;
  float s = 0.f, q = 0.f;
  for (int b = 0; b < nb; b++) { s += part[(size_t)b * 2048 + c * 2]; q += part[(size_t)b * 2048 + c * 2 + 1]; }
  float mean = s / (float)M;
  float var = q / (float)M - mean * mean;
  float sc = gamma[c] * rsqrtf(var + 1e-5f);
  scale[c] = sc; shift[c] = beta[c] - mean * sc;
}

__global__ __launch_bounds__(256) void prep_tables(const int* __restrict__ seq_idx, const int* __restrict__ lengths,
                                                   int* __restrict__ gf, int* __restrict__ gb, int* __restrict__ sb) {
  int idx = blockIdx.x * 256 + threadIdx.x;
  if (idx < 512 * 32) {
    int s = idx >> 5, t = idx & 31;
    int len = lengths[s];
    gf[idx] = (t < len) ? seq_idx[idx] : -1;
    int rb = len - 1 - t;
    gb[idx] = seq_idx[(s << 5) + (rb < 0 ? 0 : rb)];
    sb[idx] = (t < len) ? seq_idx[(s << 5) + (len - 1 - t)] : -1;
  }
}

__global__ __launch_bounds__(256) void build_wih(const float* __restrict__ wf, const float* __restrict__ wb,
                                                 const float* __restrict__ bihf, const float* __restrict__ bhhf,
                                                 const float* __restrict__ bihb, const float* __restrict__ bhhb,
                                                 const float* __restrict__ scale, const float* __restrict__ shift,
                                                 unsigned short* __restrict__ wcdst, float* __restrict__ bc,
                                                 _Float16* __restrict__ bcp) {
  int orow = blockIdx.x * 4 + (threadIdx.x >> 6);
  int l = threadIdx.x & 63;
  int dir = orow >> 11, j = orow & 2047;
  int cc = j >> 6, jj = j & 63, g = jj >> 4, u = jj & 15;
  int srow = g * 512 + cc * 16 + u;
  const float* src = (dir ? wb : wf) + (size_t)srow * 1024;
  unsigned short* dst = wcdst + (size_t)orow * 1024;
  float sacc = 0.f;
  #pragma unroll
  for (int jv = 0; jv < 16; jv++) {
    int k = l + jv * 64;
    float v = src[k];
    sacc += shift[k] * v;
    dst[k] = f2bf(v * scale[k]);
  }
  #pragma unroll
  for (int o2 = 32; o2 > 0; o2 >>= 1) sacc += __shfl_down(sacc, o2);
  if (l == 0) {
    float bb = (dir ? (bihb[srow] + bhhb[srow]) : (bihf[srow] + bhhf[srow])) + sacc;
    bc[orow] = bb;
    int pc = (dir << 11) + (((cc << 4) + u) << 2) + g;
    bcp[pc] = (_Float16)bb;
  }
}

// whhc rows: orow = d*2048 + c*128 + L, L = cgl*64 + g*16 + u -> src row g*512 + (c*32 + cgl*16 + u)
__global__ __launch_bounds__(256) void build_whh(const float* __restrict__ wf, const float* __restrict__ wb,
                                                 unsigned short* __restrict__ o) {
  int cidx = blockIdx.x * 256 + threadIdx.x;
  if (cidx < 4096 * 64) {
    int orow = cidx >> 6, k0 = (cidx & 63) * 8;
    int dir = orow >> 11, j = orow & 2047;
    int cc = j >> 7, L = j & 127;
    int cgl = L >> 6, g = (L >> 4) & 3, u = L & 15;
    int hunit = cc * 32 + cgl * 16 + u;
    const float* src = (dir ? wb : wf) + (size_t)(g * 512 + hunit) * 512 + k0;
    unsigned short* dst = o + (size_t)orow * 512 + k0;
    float4 a = *(const float4*)(src);
    float4 bq = *(const float4*)(src + 4);
    dst[0] = f2bf(a.x); dst[1] = f2bf(a.y); dst[2] = f2bf(a.z); dst[3] = f2bf(a.w);
    dst[4] = f2bf(bq.x); dst[5] = f2bf(bq.y); dst[6] = f2bf(bq.z); dst[7] = f2bf(bq.w);
  }
}

extern "C" void kernel_launch(void* const* d_in, const int* in_sizes, int n_in,
                              void* d_out, int out_size, void* d_ws, size_t ws_size,
                              hipStream_t stream) {
  const float* x     = (const float*)d_in[0];
  const float* fc1w  = (const float*)d_in[1];
  const float* fc1b  = (const float*)d_in[2];
  const float* gamma = (const float*)d_in[3];
  const float* beta  = (const float*)d_in[4];
  const float* fc2w  = (const float*)d_in[5];
  const float* fc2b  = (const float*)d_in[6];
  const float* wihf  = (const float*)d_in[7];
  const float* whhf  = (const float*)d_in[8];
  const float* bihf  = (const float*)d_in[9];
  const float* bhhf  = (const float*)d_in[10];
  const float* wihb  = (const float*)d_in[11];
  const float* whhb  = (const float*)d_in[12];
  const float* bihb  = (const float*)d_in[13];
  const float* bhhb  = (const float*)d_in[14];
  const int* seq_idx = (const int*)d_in[15];
  const int* lengths = (const int*)d_in[16];
  float* out = (float*)d_out;

  const int n = in_sizes[0] / 13824;           // 9121
  const int mt = (n + 255) / 256;              // 36 M-tiles of 256
  const int mpad = mt * 256;                   // 9216

  char* ws = (char*)d_ws;
  size_t off = 0;
  auto alloc = [&](size_t bytes) -> void* {
    void* p = ws + off; off += (bytes + 255) & ~(size_t)255; return p;
  };
  unsigned short* w1_h = (unsigned short*)alloc((size_t)1024 * 13824 * 2);
  unsigned short* w2_h = (unsigned short*)alloc((size_t)4864 * 1024 * 2);
  unsigned short* h    = (unsigned short*)alloc((size_t)mpad * 1024 * 2);
  _Float16*       G    = (_Float16*)alloc((size_t)mpad * 4096 * 2);  // also aliased as split-K partials
  unsigned short* wihc = (unsigned short*)alloc((size_t)4096 * 1024 * 2);
  unsigned short* whhc = (unsigned short*)alloc((size_t)4096 * 512 * 2);
  float* bias_c = (float*)alloc(4096 * 4);
  _Float16* bias_p = (_Float16*)alloc(4096 * 2);
  unsigned short* lfeat  = (unsigned short*)alloc((size_t)mpad * 1024 * 2);
  unsigned short* hstate = (unsigned short*)alloc((size_t)2 * 1024 * 512 * 2);
  float* part   = (float*)alloc((size_t)(mpad / 32) * 2048 * 4);
  float* scale  = (float*)alloc(1024 * 4);
  float* shift  = (float*)alloc(1024 * 4);
  int* gf  = (int*)alloc(16384 * 4);
  int* gb  = (int*)alloc(16384 * 4);
  int* sb  = (int*)alloc(16384 * 4);
  int* flags = (int*)alloc(256 * 32 * 4);

  _Float16* P16 = (_Float16*)G;   // fc1 split-K fp16 partials [3][mpad][1024] (56.6 MB <= G size 75.5 MB)

  dim3 blk(256);
  dim3 blk5(512);

  conv_bf16<<<1024, blk, 0, stream>>>(fc1w, w1_h, (size_t)1024 * 13824, (size_t)1024 * 13824);
  conv_bf16<<<256, blk, 0, stream>>>(fc2w, w2_h, (size_t)4787 * 1024, (size_t)4864 * 1024);
  build_whh<<<1024, blk, 0, stream>>>(whhf, whhb, whhc);
  prep_tables<<<64, blk, 0, stream>>>(seq_idx, lengths, gf, gb, sb);
  hipMemsetAsync(hstate, 0, (size_t)2 * 1024 * 512 * 2, stream);
  hipMemsetAsync(flags, 0, 256 * 32 * 4, stream);

  // fc1 split-K with fused f32->bf16 A conversion: P16[z] = x @ w1^T (K chunk z), z in {0,1,2}
  gemm256fA<<<dim3(4, mt, 3), blk5, 0, stream>>>(
      x, w1_h, P16, mpad, 1024, 4608, 13824, 13824, 1024, n);

  // reduce + bias + relu -> h bf16, fused BN partial sums
  fc1_reduce<<<mpad / 32, blk, 0, stream>>>(P16, fc1b, h, part, n, mpad);
  bn_final<<<4, blk, 0, stream>>>(part, gamma, beta, scale, shift, n, mpad / 32);
  build_wih<<<1024, blk, 0, stream>>>(wihf, wihb, bihf, bhhf, bihb, bhhb, scale, shift, wihc, bias_c, bias_p);

  // G = feats @ wih_c^T + bias_c -> fp16, unit-packed (BN folded; overwrites P16 after it's consumed)
  gemm256<3><<<dim3(16, mt), blk5, 0, stream>>>(
      h, wihc, G, n, 4096, 1024, 1024, 1024, 4096, bias_c);

  // fused persistent bidirectional LSTM (32 steps)
  lstm_persist<<<256, blk, 0, stream>>>(whhc, (const unsigned short*)bias_p, G, gf, gb, sb,
                                        hstate, lfeat, flags);

  // fc2: out = lstm_feats @ fc2w^T + b
  gemm256<0><<<dim3(19, mt), blk5, 0, stream>>>(
      lfeat, w2_h, out, n, 4787, 1024, 1024, 1024, 4787, fc2b);
}

// Round 10
// 1043.862 us; speedup vs baseline: 1.0839x; 1.0441x over previous
//
#include <hip/hip_runtime.h>

typedef short short8v __attribute__((ext_vector_type(8)));
typedef float f32x4 __attribute__((ext_vector_type(4)));
typedef _Float16 h4v __attribute__((ext_vector_type(4)));

__device__ __forceinline__ unsigned short f2bf(float f){
  unsigned int u = __float_as_uint(f);
  u += 0x7fffu + ((u >> 16) & 1u);
  return (unsigned short)(u >> 16);
}
__device__ __forceinline__ float bf2f(unsigned short h){
  return __uint_as_float(((unsigned int)h) << 16);
}
union H2F { unsigned short u; _Float16 h; };
__device__ __forceinline__ float fp16f(unsigned short b){ H2F t; t.u = b; return (float)t.h; }
__device__ __forceinline__ float fast_tanh(float x){
  // exact at +/-inf (expf -> inf/0 => +/-1); ~1e-7 abs err, << bf16 rounding
  return 1.f - 2.f / (1.f + __expf(2.f * x));
}

typedef __attribute__((address_space(1))) const unsigned int gu32;
typedef __attribute__((address_space(3))) unsigned int lu32;
__device__ __forceinline__ void gl16(const void* g, void* l){
  __builtin_amdgcn_global_load_lds((gu32*)g, (lu32*)l, 16, 0, 0);
}

// ========== 256x256 GEMM: C = A @ B^T, bf16 in; 4-phase staggered prefetch (proven schedule) ==========
// EPI 0: +bias -> f32 (fc2) | EPI 3: +bias -> fp16 unit-packed (G)
template<int EPI>
__global__ __launch_bounds__(512, 2)
void gemm256(const unsigned short* __restrict__ A, const unsigned short* __restrict__ B,
             void* __restrict__ Cout, int M, int N, int K, int lda, int ldb, int ldc,
             const float* __restrict__ bias)
{
  __shared__ __align__(16) unsigned short As[2 * 2 * 256 * 32];   // 64 KB
  __shared__ __align__(16) unsigned short Bs[2 * 2 * 256 * 32];   // 64 KB

  const int tid = threadIdx.x;
  const int gx = gridDim.x;
  const int nwg = gx * gridDim.y;
  int dd = blockIdx.y * gx + blockIdx.x;
  int q8 = nwg >> 3, r8 = nwg & 7, xc = dd & 7, t8 = dd >> 3;
  int Lid = (xc < r8 ? xc * (q8 + 1) : r8 * (q8 + 1) + (xc - r8) * q8) + t8;
  const int bcol = (Lid % gx) * 256;
  const int brow = (Lid / gx) * 256;

  const int l = tid & 63, w = tid >> 6;
  const int wr = w >> 2;                 // M half (0..1)
  const int wn = w & 3;                  // N quarter (0..3)
  const int r16 = l & 15, kg = l >> 4;
  const int swz = (r16 >> 1) & 3;
  const int srow4 = l >> 2, sblk = l & 3;
  const int scol = (sblk ^ ((l >> 3) & 3)) * 8;

  const int kz = blockIdx.z * K;
  const unsigned short* Ag = A + (size_t)(brow + w * 32 + srow4) * lda + kz + scol;
  const unsigned short* Bg = B + (size_t)(bcol + w * 32 + srow4) * ldb + kz + scol;
  unsigned short* Asd = As + w * 1024;
  unsigned short* Bsd = Bs + w * 1024;

#define STA(buf, kh, kt) do { \
    gl16(Ag + (size_t)(kt) * 64 + (kh) * 32, Asd + (buf) * 16384 + (kh) * 8192); \
    gl16(Ag + (size_t)(kt) * 64 + (kh) * 32 + (size_t)16 * lda, Asd + (buf) * 16384 + (kh) * 8192 + 512); \
  } while (0)
#define STB(buf, kh, kt) do { \
    gl16(Bg + (size_t)(kt) * 64 + (kh) * 32, Bsd + (buf) * 16384 + (kh) * 8192); \
    gl16(Bg + (size_t)(kt) * 64 + (kh) * 32 + (size_t)16 * ldb, Bsd + (buf) * 16384 + (kh) * 8192 + 512); \
  } while (0)

  const unsigned short* Ard = As + (wr * 128 + r16) * 32 + ((kg ^ swz) * 8);
  const unsigned short* Brd = Bs + (wn * 64 + r16) * 32 + ((kg ^ swz) * 8);

  f32x4 acc[8][4];
  #pragma unroll
  for (int m = 0; m < 8; m++)
    #pragma unroll
    for (int nn = 0; nn < 4; nn++) { f32x4 z = {0.f, 0.f, 0.f, 0.f}; acc[m][nn] = z; }

  short8v af[4], bfr[4];

#define LDA4(c, kk, mq) { \
    _Pragma("unroll") for (int i = 0; i < 4; i++) \
      af[i] = *(const short8v*)(Ard + (c) * 16384 + (kk) * 8192 + ((mq) * 4 + i) * 512); }
#define LDB4(c, kk) { \
    _Pragma("unroll") for (int nn = 0; nn < 4; nn++) \
      bfr[nn] = *(const short8v*)(Brd + (c) * 16384 + (kk) * 8192 + nn * 512); }
#define MFMAQ(mq) { \
    __builtin_amdgcn_s_setprio(1); \
    _Pragma("unroll") for (int i = 0; i < 4; i++) { \
      _Pragma("unroll") for (int nn = 0; nn < 4; nn++) \
        acc[(mq) * 4 + i][nn] = __builtin_amdgcn_mfma_f32_16x16x32_bf16(af[i], bfr[nn], acc[(mq) * 4 + i][nn], 0, 0, 0); \
    } \
    __builtin_amdgcn_s_setprio(0); }

  const int nk = K >> 6;
  STA(0, 0, 0); STB(0, 0, 0); STA(0, 1, 0); STB(0, 1, 0);
  asm volatile("s_waitcnt vmcnt(4)" ::: "memory");
  __builtin_amdgcn_s_barrier();
  __builtin_amdgcn_sched_barrier(0);

  for (int j = 0; j < nk; j++) {
    const int c = j & 1, nb = c ^ 1;
    const bool pf = (j + 1 < nk);
    // phase 1
    LDB4(c, 0); LDA4(c, 0, 0);
    if (pf) STA(nb, 0, j + 1);
    __builtin_amdgcn_s_barrier();
    MFMAQ(0);
    __builtin_amdgcn_s_barrier();
    // phase 2
    LDA4(c, 0, 1);
    if (pf) STB(nb, 0, j + 1);
    __builtin_amdgcn_s_barrier();
    MFMAQ(1);
    if (pf) asm volatile("s_waitcnt vmcnt(4)" ::: "memory");
    else    asm volatile("s_waitcnt vmcnt(0)" ::: "memory");
    __builtin_amdgcn_s_barrier();
    __builtin_amdgcn_sched_barrier(0);
    // phase 3
    LDB4(c, 1); LDA4(c, 1, 0);
    if (pf) STA(nb, 1, j + 1);
    __builtin_amdgcn_s_barrier();
    MFMAQ(0);
    __builtin_amdgcn_s_barrier();
    // phase 4
    LDA4(c, 1, 1);
    if (pf) STB(nb, 1, j + 1);
    __builtin_amdgcn_s_barrier();
    MFMAQ(1);
    if (pf) asm volatile("s_waitcnt vmcnt(4)" ::: "memory");
    __builtin_amdgcn_s_barrier();
    __builtin_amdgcn_sched_barrier(0);
  }
#undef STA
#undef STB
#undef LDA4
#undef LDB4
#undef MFMAQ

  // C/D map: col = lane&15, row = (lane>>4)*4 + reg
  #pragma unroll
  for (int m = 0; m < 8; m++) {
    const int row0 = brow + wr * 128 + m * 16 + kg * 4;
    #pragma unroll
    for (int nn = 0; nn < 4; nn++) {
      const int col = bcol + wn * 64 + nn * 16 + r16;
      if (col < N) {
        const float bv = bias[col];
        #pragma unroll
        for (int rr = 0; rr < 4; rr++) {
          const int row = row0 + rr;
          if (row < M) {
            float val = acc[m][nn][rr] + bv;
            if (EPI == 3) {
              int dL = col >> 11, rc = col & 2047;
              int cg = rc >> 6, g = (rc >> 4) & 3, u = rc & 15;
              int pc = (dL << 11) + (((cg << 4) + u) << 2) + g;
              ((_Float16*)Cout)[(size_t)row * ldc + pc] = (_Float16)val;
            } else {
              ((float*)Cout)[(size_t)row * ldc + col] = val;
            }
          }
        }
      }
    }
  }
}

// ========== fc1 GEMM with fused f32->bf16 A conversion (proven round-5 schedule) ==========
__global__ __launch_bounds__(512, 2)
void gemm256fA(const float* __restrict__ A, const unsigned short* __restrict__ B,
               _Float16* __restrict__ Cout, int M, int N, int K, int lda, int ldb, int ldc,
               int nvalid)
{
  __shared__ __align__(16) unsigned short As[2 * 2 * 256 * 32];   // 64 KB
  __shared__ __align__(16) unsigned short Bs[2 * 2 * 256 * 32];   // 64 KB

  const int tid = threadIdx.x;
  const int gx = gridDim.x;
  const int nwg = gx * gridDim.y;
  int dd = blockIdx.y * gx + blockIdx.x;
  int q8 = nwg >> 3, r8 = nwg & 7, xc = dd & 7, t8 = dd >> 3;
  int Lid = (xc < r8 ? xc * (q8 + 1) : r8 * (q8 + 1) + (xc - r8) * q8) + t8;
  const int bcol = (Lid % gx) * 256;
  const int brow = (Lid / gx) * 256;

  const int l = tid & 63, w = tid >> 6;
  const int wr = w >> 2;
  const int wn = w & 3;
  const int r16 = l & 15, kg = l >> 4;
  const int swz = (r16 >> 1) & 3;
  const int srow4 = l >> 2, sblk = l & 3;
  const int scol = (sblk ^ ((l >> 3) & 3)) * 8;

  const int kz = blockIdx.z * K;
  const unsigned short* Bg = B + (size_t)(bcol + w * 32 + srow4) * ldb + kz + scol;
  unsigned short* Bsd = Bs + w * 1024;

#define STB(buf, kh, kt) do { \
    gl16(Bg + (size_t)(kt) * 64 + (kh) * 32, Bsd + (buf) * 16384 + (kh) * 8192); \
    gl16(Bg + (size_t)(kt) * 64 + (kh) * 32 + (size_t)16 * ldb, Bsd + (buf) * 16384 + (kh) * 8192 + 512); \
  } while (0)

  // --- A reg-staging geometry: lane -> (row, 8-f32 granule), q = 0..3 ---
  const int rsel8 = l >> 3;         // 0..7 row within 8-row group
  const int g8 = l & 7;             // granule of 8 consecutive f32 within the 64-k tile
  unsigned long long abase[4];
  int dstA[4];
  #pragma unroll
  for (int q = 0; q < 4; q++) {
    int row_local = w * 32 + q * 8 + rsel8;
    int rowA = brow + row_local;
    if (rowA >= nvalid) rowA = nvalid - 1;
    abase[q] = (unsigned long long)(A + (size_t)rowA * lda + kz + g8 * 8);
    int kh = g8 >> 2, gA = g8 & 3, swi = (row_local >> 1) & 3;
    dstA[q] = kh * 8192 + row_local * 32 + ((gA ^ swi) * 8);
  }

  const unsigned short* Ard = As + (wr * 128 + r16) * 32 + ((kg ^ swz) * 8);
  const unsigned short* Brd = Bs + (wn * 64 + r16) * 32 + ((kg ^ swz) * 8);

  f32x4 acc[8][4];
  #pragma unroll
  for (int m = 0; m < 8; m++)
    #pragma unroll
    for (int nn = 0; nn < 4; nn++) { f32x4 z = {0.f, 0.f, 0.f, 0.f}; acc[m][nn] = z; }

  short8v af[4], bfr[4];
  f32x4 ar[4][2];

#define ALOAD(kt) { \
    _Pragma("unroll") for (int q = 0; q < 4; q++) { \
      unsigned long long aq = abase[q] + (unsigned long long)(kt) * 256; \
      asm volatile("global_load_dwordx4 %0, %1, off" : "=v"(ar[q][0]) : "v"(aq) : "memory"); \
      asm volatile("global_load_dwordx4 %0, %1, off offset:16" : "=v"(ar[q][1]) : "v"(aq) : "memory"); \
    } }
#define AWRITE(buf) { \
    _Pragma("unroll") for (int q = 0; q < 4; q++) { \
      unsigned int d0_, d1_, d2_, d3_; \
      asm("v_cvt_pk_bf16_f32 %0, %1, %2" : "=v"(d0_) : "v"(ar[q][0][0]), "v"(ar[q][0][1])); \
      asm("v_cvt_pk_bf16_f32 %0, %1, %2" : "=v"(d1_) : "v"(ar[q][0][2]), "v"(ar[q][0][3])); \
      asm("v_cvt_pk_bf16_f32 %0, %1, %2" : "=v"(d2_) : "v"(ar[q][1][0]), "v"(ar[q][1][1])); \
      asm("v_cvt_pk_bf16_f32 %0, %1, %2" : "=v"(d3_) : "v"(ar[q][1][2]), "v"(ar[q][1][3])); \
      uint4 pv_; pv_.x = d0_; pv_.y = d1_; pv_.z = d2_; pv_.w = d3_; \
      *(uint4*)(As + (buf) * 16384 + dstA[q]) = pv_; \
    } }

  const int nk = K >> 6;
  // prologue: A tile0 (reg) + B tile0 (gl16, both pieces)
  ALOAD(0);
  STB(0, 0, 0); STB(0, 1, 0);
  asm volatile("s_waitcnt vmcnt(4)" ::: "memory");   // retire A loads (4 B gl16 remain)
  __builtin_amdgcn_sched_barrier(0);
  AWRITE(0);
  asm volatile("s_waitcnt vmcnt(0) lgkmcnt(0)" ::: "memory");
  __builtin_amdgcn_s_barrier();
  __builtin_amdgcn_sched_barrier(0);

#define LDA4(c, kk, mq) { \
    _Pragma("unroll") for (int i = 0; i < 4; i++) \
      af[i] = *(const short8v*)(Ard + (c) * 16384 + (kk) * 8192 + ((mq) * 4 + i) * 512); }
#define LDB4(c, kk) { \
    _Pragma("unroll") for (int nn = 0; nn < 4; nn++) \
      bfr[nn] = *(const short8v*)(Brd + (c) * 16384 + (kk) * 8192 + nn * 512); }
#define MFMAQ(mq) { \
    __builtin_amdgcn_s_setprio(1); \
    _Pragma("unroll") for (int i = 0; i < 4; i++) { \
      _Pragma("unroll") for (int nn = 0; nn < 4; nn++) \
        acc[(mq) * 4 + i][nn] = __builtin_amdgcn_mfma_f32_16x16x32_bf16(af[i], bfr[nn], acc[(mq) * 4 + i][nn], 0, 0, 0); \
    } \
    __builtin_amdgcn_s_setprio(0); }

  for (int j = 0; j < nk; j++) {
    const int c = j & 1, nb = c ^ 1;
    const bool pf = (j + 1 < nk);
    // phase 1: issue A loads for j+1 (oldest VMEM, 8 ops)
    LDB4(c, 0); LDA4(c, 0, 0);
    if (pf) ALOAD(j + 1);
    __builtin_amdgcn_s_barrier();
    MFMAQ(0);
    __builtin_amdgcn_s_barrier();
    // phase 2: stage BOTH B pieces for j+1 (4 gl16)
    LDA4(c, 0, 1);
    if (pf) { STB(nb, 0, j + 1); STB(nb, 1, j + 1); }
    __builtin_amdgcn_s_barrier();
    MFMAQ(1);
    __builtin_amdgcn_s_barrier();
    __builtin_amdgcn_sched_barrier(0);
    // phase 3: retire A loads (2 phases of slack), convert + b128 write
    LDB4(c, 1); LDA4(c, 1, 0);
    if (pf) {
      asm volatile("s_waitcnt vmcnt(4)" ::: "memory");
      __builtin_amdgcn_sched_barrier(0);
      AWRITE(nb);
    }
    __builtin_amdgcn_s_barrier();
    MFMAQ(0);
    __builtin_amdgcn_s_barrier();
    // phase 4: drain B (staged 2 phases ago) + ds_writes before the buffer-swap barrier
    LDA4(c, 1, 1);
    __builtin_amdgcn_s_barrier();
    MFMAQ(1);
    asm volatile("s_waitcnt vmcnt(0) lgkmcnt(0)" ::: "memory");
    __builtin_amdgcn_s_barrier();
    __builtin_amdgcn_sched_barrier(0);
  }
#undef STB
#undef ALOAD
#undef AWRITE
#undef LDA4
#undef LDB4
#undef MFMAQ

  // epilogue: raw fp16 partial
  #pragma unroll
  for (int m = 0; m < 8; m++) {
    const int row0 = brow + wr * 128 + m * 16 + kg * 4;
    #pragma unroll
    for (int nn = 0; nn < 4; nn++) {
      const int col = bcol + wn * 64 + nn * 16 + r16;
      if (col < N) {
        #pragma unroll
        for (int rr = 0; rr < 4; rr++) {
          const int row = row0 + rr;
          if (row < M)
            Cout[(size_t)blockIdx.z * M * ldc + (size_t)row * ldc + col] = (_Float16)(acc[m][nn][rr]);
        }
      }
    }
  }
}

// ========== fc1 split-K reduce: h = relu(P0+P1+P2+bias) -> bf16, fused BN partial sums ==========
__global__ __launch_bounds__(256) void fc1_reduce(const _Float16* __restrict__ P, const float* __restrict__ bias,
                                                  unsigned short* __restrict__ h, float* __restrict__ part,
                                                  int n, int mpad) {
  int b = blockIdx.x, tid = threadIdx.x;
  int c0 = tid * 4;
  float4 bsv = *(const float4*)(bias + c0);
  float s[4] = {0,0,0,0}, qq[4] = {0,0,0,0};
  int rbeg = b * 32;
  for (int r = rbeg; r < rbeg + 32; r++) {
    h4v a0 = *(const h4v*)(P + (size_t)r * 1024 + c0);
    h4v a1 = *(const h4v*)(P + ((size_t)mpad + r) * 1024 + c0);
    h4v a2 = *(const h4v*)(P + ((size_t)2 * mpad + r) * 1024 + c0);
    float v0 = fmaxf((float)a0[0] + (float)a1[0] + (float)a2[0] + bsv.x, 0.f);
    float v1 = fmaxf((float)a0[1] + (float)a1[1] + (float)a2[1] + bsv.y, 0.f);
    float v2 = fmaxf((float)a0[2] + (float)a1[2] + (float)a2[2] + bsv.z, 0.f);
    float v3 = fmaxf((float)a0[3] + (float)a1[3] + (float)a2[3] + bsv.w, 0.f);
    if (r < n) {
      s[0] += v0; qq[0] += v0 * v0;
      s[1] += v1; qq[1] += v1 * v1;
      s[2] += v2; qq[2] += v2 * v2;
      s[3] += v3; qq[3] += v3 * v3;
    }
    *(ushort4*)(h + (size_t)r * 1024 + c0) = make_ushort4(f2bf(v0), f2bf(v1), f2bf(v2), f2bf(v3));
  }
  float* pp = part + (size_t)b * 2048;
  #pragma unroll
  for (int k = 0; k < 4; k++) { pp[(c0 + k) * 2] = s[k]; pp[(c0 + k) * 2 + 1] = qq[k]; }
}

// ================= persistent fused bidirectional LSTM =================
__global__ __launch_bounds__(256, 1)
void lstm_persist(const unsigned short* __restrict__ whhc, const unsigned short* __restrict__ bcp,
                  const _Float16* __restrict__ G,
                  const int* __restrict__ gf, const int* __restrict__ gb, const int* __restrict__ sb,
                  unsigned short* __restrict__ hst,
                  unsigned short* __restrict__ lfeat, int* __restrict__ flags)
{
  __shared__ __align__(16) unsigned short Bsh[128 * 512];   // 128 KB resident whh tile
  const int tid = threadIdx.x;
  const int l = tid & 63, w = tid >> 6;
  const int b = blockIdx.x;
  const int grp = b & 15;          // (d, rg)
  const int c = b >> 4;            // 0..15 h-col block
  const int d = grp >> 3;
  const int rowbase = d * 512 + (grp & 7) * 64;
  const int r16 = l & 15, kg = l >> 4;
  const int swzl = (r16 & 7) * 8;
  const int hu0 = c * 32 + r16;

  const unsigned short* Bsrc = whhc + ((size_t)(d * 2048 + c * 128)) * 512;
  #pragma unroll
  for (int i = 0; i < 32; i++) {
    int rr = w * 32 + i;
    gl16(Bsrc + (size_t)rr * 512 + ((l * 8) ^ ((rr & 7) * 8)), Bsh + rr * 512);
  }
  asm volatile("s_waitcnt vmcnt(0)");
  __syncthreads();

  float creg[2][4];
  #pragma unroll
  for (int m = 0; m < 2; m++)
    #pragma unroll
    for (int rr = 0; rr < 4; rr++) creg[m][rr] = 0.f;

  const size_t stbase = (size_t)(((grp * 4 + w) * 16 + c) * 4 + (r16 >> 3)) * 128 + (size_t)kg * 32 + (r16 & 7);
  const size_t ldbase = ((size_t)(grp * 64 + w * 16) * 1024) + (size_t)l * 16;

  for (int t = 0; t < 32; t++) {
    ushort4 gv[2][4];
    int scv[4];
    #pragma unroll
    for (int rr = 0; rr < 4; rr++) {
      int row = rowbase + w * 16 + kg * 4 + rr;
      int sq = row & 511;
      int gi = d ? gb[sq * 32 + t] : gf[sq * 32 + t];
      const unsigned short* src = (gi >= 0)
          ? (const unsigned short*)G + ((size_t)gi * 4096 + (d << 11))
          : bcp + (d << 11);
      gv[0][rr] = *(const ushort4*)(src + hu0 * 4);
      gv[1][rr] = *(const ushort4*)(src + (hu0 + 16) * 4);
      scv[rr] = d ? sb[sq * 32 + t] : gi;
    }

    if (t > 0) {
      while (true) {
        int fv = 0x7fffffff;
        if (l < 16)
          fv = __hip_atomic_load(flags + ((grp * 16 + l) << 5), __ATOMIC_RELAXED, __HIP_MEMORY_SCOPE_AGENT);
        if (__all(fv >= t)) break;
        __builtin_amdgcn_s_sleep(1);
      }
    }
    asm volatile("" ::: "memory");

    const unsigned short* hp = hst + (size_t)(t & 1) * 524288;
    unsigned short* hn = hst + (size_t)((t + 1) & 1) * 524288;

    short8v av[16];
    {
      unsigned long long a64 = (unsigned long long)((const char*)hp + ldbase);
      #pragma unroll
      for (int kq = 0; kq < 4; kq++) {
        unsigned long long aq = a64 + (unsigned long long)kq * 4096;
        asm volatile("global_load_dwordx4 %0, %1, off offset:0 sc0 sc1"
                     : "=v"(av[kq * 4 + 0]) : "v"(aq) : "memory");
        asm volatile("global_load_dwordx4 %0, %1, off offset:1024 sc0 sc1"
                     : "=v"(av[kq * 4 + 1]) : "v"(aq) : "memory");
        asm volatile("global_load_dwordx4 %0, %1, off offset:2048 sc0 sc1"
                     : "=v"(av[kq * 4 + 2]) : "v"(aq) : "memory");
        asm volatile("global_load_dwordx4 %0, %1, off offset:3072 sc0 sc1"
                     : "=v"(av[kq * 4 + 3]) : "v"(aq) : "memory");
      }
    }
    asm volatile("s_waitcnt vmcnt(0)" ::: "memory");

    f32x4 acc[8];
    #pragma unroll
    for (int nn = 0; nn < 8; nn++) { f32x4 z = {0.f, 0.f, 0.f, 0.f}; acc[nn] = z; }

    #pragma unroll
    for (int kc = 0; kc < 8; kc++) {
      short8v bv[8][2];
      #pragma unroll
      for (int nn = 0; nn < 8; nn++)
        #pragma unroll
        for (int kk = 0; kk < 2; kk++)
          bv[nn][kk] = *(const short8v*)(Bsh + (nn * 16 + r16) * 512 + ((kc * 64 + kk * 32 + kg * 8) ^ swzl));
      #pragma unroll
      for (int kk = 0; kk < 2; kk++)
        #pragma unroll
        for (int nn = 0; nn < 8; nn++)
          acc[nn] = __builtin_amdgcn_mfma_f32_16x16x32_bf16(av[kc * 2 + kk], bv[nn][kk], acc[nn], 0, 0, 0);
    }

    unsigned long long ha = (unsigned long long)((char*)hn + stbase * 2);
    #pragma unroll
    for (int cgl = 0; cgl < 2; cgl++) {
      const int hu = hu0 + cgl * 16;
      #pragma unroll
      for (int reg = 0; reg < 4; reg++) {
        float g_i = acc[cgl * 4 + 0][reg] + fp16f(gv[cgl][reg].x);
        float g_f = acc[cgl * 4 + 1][reg] + fp16f(gv[cgl][reg].y);
        float g_g = acc[cgl * 4 + 2][reg] + fp16f(gv[cgl][reg].z);
        float g_o = acc[cgl * 4 + 3][reg] + fp16f(gv[cgl][reg].w);
        float si = 1.f / (1.f + __expf(-g_i));
        float sf = 1.f / (1.f + __expf(-g_f));
        float so = 1.f / (1.f + __expf(-g_o));
        float cn = sf * creg[cgl][reg] + si * fast_tanh(g_g);
        float hnv = so * fast_tanh(cn);
        creg[cgl][reg] = cn;
        unsigned int hb = f2bf(hnv);
        if (cgl == 0) {
          if (reg == 0) asm volatile("global_store_short %0, %1, off offset:0 sc0 sc1" :: "v"(ha), "v"(hb) : "memory");
          if (reg == 1) asm volatile("global_store_short %0, %1, off offset:16 sc0 sc1" :: "v"(ha), "v"(hb) : "memory");
          if (reg == 2) asm volatile("global_store_short %0, %1, off offset:32 sc0 sc1" :: "v"(ha), "v"(hb) : "memory");
          if (reg == 3) asm volatile("global_store_short %0, %1, off offset:48 sc0 sc1" :: "v"(ha), "v"(hb) : "memory");
        } else {
          if (reg == 0) asm volatile("global_store_short %0, %1, off offset:512 sc0 sc1" :: "v"(ha), "v"(hb) : "memory");
          if (reg == 1) asm volatile("global_store_short %0, %1, off offset:528 sc0 sc1" :: "v"(ha), "v"(hb) : "memory");
          if (reg == 2) asm volatile("global_store_short %0, %1, off offset:544 sc0 sc1" :: "v"(ha), "v"(hb) : "memory");
          if (reg == 3) asm volatile("global_store_short %0, %1, off offset:560 sc0 sc1" :: "v"(ha), "v"(hb) : "memory");
        }
        int sc = scv[reg];
        if (sc >= 0) lfeat[(size_t)sc * 1024 + d * 512 + hu] = f2bf(hnv);
      }
    }

    __syncthreads();
    if (t < 31 && tid == 0)
      __hip_atomic_store(flags + ((grp * 16 + c) << 5), t + 1, __ATOMIC_RELAXED, __HIP_MEMORY_SCOPE_AGENT);
  }
}

// ================= merged prologue: conv w1 + conv w2 + build_whh + prep_tables + zeroing =================
__device__ __forceinline__ void conv_seg(const float* __restrict__ src, unsigned short* __restrict__ dst,
                                         size_t nvalid, size_t total, int vb, int nb) {
  size_t stride = (size_t)nb * 2048;
  for (size_t i = ((size_t)vb * 256 + threadIdx.x) * 8; i < total; i += stride) {
    unsigned short o[8];
    if (i + 8 <= nvalid) {
      float4 a = *(const float4*)(src + i);
      float4 b = *(const float4*)(src + i + 4);
      o[0] = f2bf(a.x); o[1] = f2bf(a.y); o[2] = f2bf(a.z); o[3] = f2bf(a.w);
      o[4] = f2bf(b.x); o[5] = f2bf(b.y); o[6] = f2bf(b.z); o[7] = f2bf(b.w);
    } else {
      #pragma unroll
      for (int j = 0; j < 8; j++) o[j] = (i + j < nvalid) ? f2bf(src[i + j]) : (unsigned short)0;
    }
    *(ushort4*)(dst + i) = make_ushort4(o[0], o[1], o[2], o[3]);
    *(ushort4*)(dst + i + 4) = make_ushort4(o[4], o[5], o[6], o[7]);
  }
}

__global__ __launch_bounds__(256)
void prep_all(const float* __restrict__ fc1w, unsigned short* __restrict__ w1_h,
              const float* __restrict__ fc2w, unsigned short* __restrict__ w2_h,
              const float* __restrict__ whhf, const float* __restrict__ whhb,
              unsigned short* __restrict__ whhc,
              const int* __restrict__ seq_idx, const int* __restrict__ lengths,
              int* __restrict__ gf, int* __restrict__ gb, int* __restrict__ sb,
              unsigned short* __restrict__ hstate, int* __restrict__ flags)
{
  const int b = blockIdx.x;
  if (b < 1024) {
    // conv w1: 1024x13824 f32 -> bf16
    conv_seg(fc1w, w1_h, (size_t)1024 * 13824, (size_t)1024 * 13824, b, 1024);
  } else if (b < 1280) {
    // conv w2: 4787x1024 valid of 4864x1024
    conv_seg(fc2w, w2_h, (size_t)4787 * 1024, (size_t)4864 * 1024, b - 1024, 256);
  } else if (b < 2304) {
    // build_whh: orow = d*2048 + c*128 + L, L = cgl*64 + g*16 + u -> src row g*512 + (c*32+cgl*16+u)
    int cidx = (b - 1280) * 256 + threadIdx.x;
    int orow = cidx >> 6, k0 = (cidx & 63) * 8;
    int dir = orow >> 11, j = orow & 2047;
    int cc = j >> 7, L = j & 127;
    int cgl = L >> 6, g = (L >> 4) & 3, u = L & 15;
    int hunit = cc * 32 + cgl * 16 + u;
    const float* src = (dir ? whhb : whhf) + (size_t)(g * 512 + hunit) * 512 + k0;
    unsigned short* dst = whhc + (size_t)orow * 512 + k0;
    float4 a = *(const float4*)(src);
    float4 bq = *(const float4*)(src + 4);
    dst[0] = f2bf(a.x); dst[1] = f2bf(a.y); dst[2] = f2bf(a.z); dst[3] = f2bf(a.w);
    dst[4] = f2bf(bq.x); dst[5] = f2bf(bq.y); dst[6] = f2bf(bq.z); dst[7] = f2bf(bq.w);
  } else if (b < 2368) {
    // prep_tables
    int idx = (b - 2304) * 256 + threadIdx.x;
    int s = idx >> 5, t = idx & 31;
    int len = lengths[s];
    gf[idx] = (t < len) ? seq_idx[idx] : -1;
    int rb = len - 1 - t;
    gb[idx] = seq_idx[(s << 5) + (rb < 0 ? 0 : rb)];
    sb[idx] = (t < len) ? seq_idx[(s << 5) + (len - 1 - t)] : -1;
  } else if (b < 2496) {
    // zero hstate: 2*1024*512*2 B = 131072 x 16B
    uint4 z = {0u, 0u, 0u, 0u};
    uint4* p = (uint4*)hstate;
    for (int i = (b - 2368) * 256 + threadIdx.x; i < 131072; i += 128 * 256)
      p[i] = z;
  } else {
    // zero flags: 256*32*4 B = 2048 x 16B (8 blocks x 256 threads, one uint4 each)
    uint4 z = {0u, 0u, 0u, 0u};
    int i = (b - 2496) * 256 + threadIdx.x;
    if (i < 2048) ((uint4*)flags)[i] = z;
  }
}

// ================= remaining helpers =================
__global__ __launch_bounds__(256) void bn_final(const float* __restrict__ part, const float* __restrict__ gamma,
                                                const float* __restrict__ beta, float* __restrict__ scale,
                                                float* __restrict__ shift, int M, int nb) {
  int c = blockIdx.x * 256 + threadIdx.x;
  float s = 0.f, q = 0.f;
  for (int b = 0; b < nb; b++) { s += part[(size_t)b * 2048 + c * 2]; q += part[(size_t)b * 2048 + c * 2 + 1]; }
  float mean = s / (float)M;
  float var = q / (float)M - mean * mean;
  float sc = gamma[c] * rsqrtf(var + 1e-5f);
  scale[c] = sc; shift[c] = beta[c] - mean * sc;
}

__global__ __launch_bounds__(256) void build_wih(const float* __restrict__ wf, const float* __restrict__ wb,
                                                 const float* __restrict__ bihf, const float* __restrict__ bhhf,
                                                 const float* __restrict__ bihb, const float* __restrict__ bhhb,
                                                 const float* __restrict__ scale, const float* __restrict__ shift,
                                                 unsigned short* __restrict__ wcdst, float* __restrict__ bc,
                                                 _Float16* __restrict__ bcp) {
  int orow = blockIdx.x * 4 + (threadIdx.x >> 6);
  int l = threadIdx.x & 63;
  int dir = orow >> 11, j = orow & 2047;
  int cc = j >> 6, jj = j & 63, g = jj >> 4, u = jj & 15;
  int srow = g * 512 + cc * 16 + u;
  const float* src = (dir ? wb : wf) + (size_t)srow * 1024;
  unsigned short* dst = wcdst + (size_t)orow * 1024;
  float sacc = 0.f;
  #pragma unroll
  for (int jv = 0; jv < 16; jv++) {
    int k = l + jv * 64;
    float v = src[k];
    sacc += shift[k] * v;
    dst[k] = f2bf(v * scale[k]);
  }
  #pragma unroll
  for (int o2 = 32; o2 > 0; o2 >>= 1) sacc += __shfl_down(sacc, o2);
  if (l == 0) {
    float bb = (dir ? (bihb[srow] + bhhb[srow]) : (bihf[srow] + bhhf[srow])) + sacc;
    bc[orow] = bb;
    int pc = (dir << 11) + (((cc << 4) + u) << 2) + g;
    bcp[pc] = (_Float16)bb;
  }
}

extern "C" void kernel_launch(void* const* d_in, const int* in_sizes, int n_in,
                              void* d_out, int out_size, void* d_ws, size_t ws_size,
                              hipStream_t stream) {
  const float* x     = (const float*)d_in[0];
  const float* fc1w  = (const float*)d_in[1];
  const float* fc1b  = (const float*)d_in[2];
  const float* gamma = (const float*)d_in[3];
  const float* beta  = (const float*)d_in[4];
  const float* fc2w  = (const float*)d_in[5];
  const float* fc2b  = (const float*)d_in[6];
  const float* wihf  = (const float*)d_in[7];
  const float* whhf  = (const float*)d_in[8];
  const float* bihf  = (const float*)d_in[9];
  const float* bhhf  = (const float*)d_in[10];
  const float* wihb  = (const float*)d_in[11];
  const float* whhb  = (const float*)d_in[12];
  const float* bihb  = (const float*)d_in[13];
  const float* bhhb  = (const float*)d_in[14];
  const int* seq_idx = (const int*)d_in[15];
  const int* lengths = (const int*)d_in[16];
  float* out = (float*)d_out;

  const int n = in_sizes[0] / 13824;           // 9121
  const int mt = (n + 255) / 256;              // 36 M-tiles of 256
  const int mpad = mt * 256;                   // 9216

  char* ws = (char*)d_ws;
  size_t off = 0;
  auto alloc = [&](size_t bytes) -> void* {
    void* p = ws + off; off += (bytes + 255) & ~(size_t)255; return p;
  };
  unsigned short* w1_h = (unsigned short*)alloc((size_t)1024 * 13824 * 2);
  unsigned short* w2_h = (unsigned short*)alloc((size_t)4864 * 1024 * 2);
  unsigned short* h    = (unsigned short*)alloc((size_t)mpad * 1024 * 2);
  _Float16*       G    = (_Float16*)alloc((size_t)mpad * 4096 * 2);  // also aliased as split-K partials
  unsigned short* wihc = (unsigned short*)alloc((size_t)4096 * 1024 * 2);
  unsigned short* whhc = (unsigned short*)alloc((size_t)4096 * 512 * 2);
  float* bias_c = (float*)alloc(4096 * 4);
  _Float16* bias_p = (_Float16*)alloc(4096 * 2);
  unsigned short* lfeat  = (unsigned short*)alloc((size_t)mpad * 1024 * 2);
  unsigned short* hstate = (unsigned short*)alloc((size_t)2 * 1024 * 512 * 2);
  float* part   = (float*)alloc((size_t)(mpad / 32) * 2048 * 4);
  float* scale  = (float*)alloc(1024 * 4);
  float* shift  = (float*)alloc(1024 * 4);
  int* gf  = (int*)alloc(16384 * 4);
  int* gb  = (int*)alloc(16384 * 4);
  int* sb  = (int*)alloc(16384 * 4);
  int* flags = (int*)alloc(256 * 32 * 4);

  _Float16* P16 = (_Float16*)G;   // fc1 split-K fp16 partials [3][mpad][1024] (56.6 MB <= G size 75.5 MB)

  dim3 blk(256);
  dim3 blk5(512);

  // merged prologue: conv w1 + conv w2 + build_whh + prep_tables + hstate/flags zero
  prep_all<<<2504, blk, 0, stream>>>(fc1w, w1_h, fc2w, w2_h, whhf, whhb, whhc,
                                     seq_idx, lengths, gf, gb, sb, hstate, flags);

  // fc1 split-K with fused f32->bf16 A conversion: P16[z] = x @ w1^T (K chunk z), z in {0,1,2}
  gemm256fA<<<dim3(4, mt, 3), blk5, 0, stream>>>(
      x, w1_h, P16, mpad, 1024, 4608, 13824, 13824, 1024, n);

  // reduce + bias + relu -> h bf16, fused BN partial sums
  fc1_reduce<<<mpad / 32, blk, 0, stream>>>(P16, fc1b, h, part, n, mpad);
  bn_final<<<4, blk, 0, stream>>>(part, gamma, beta, scale, shift, n, mpad / 32);
  build_wih<<<1024, blk, 0, stream>>>(wihf, wihb, bihf, bhhf, bihb, bhhb, scale, shift, wihc, bias_c, bias_p);

  // G = feats @ wih_c^T + bias_c -> fp16, unit-packed (BN folded; overwrites P16 after it's consumed)
  gemm256<3><<<dim3(16, mt), blk5, 0, stream>>>(
      h, wihc, G, n, 4096, 1024, 1024, 1024, 4096, bias_c);

  // fused persistent bidirectional LSTM (32 steps)
  lstm_persist<<<256, blk, 0, stream>>>(whhc, (const unsigned short*)bias_p, G, gf, gb, sb,
                                        hstate, lfeat, flags);

  // fc2: out = lstm_feats @ fc2w^T + b
  gemm256<0><<<dim3(19, mt), blk5, 0, stream>>>(
      lfeat, w2_h, out, n, 4787, 1024, 1024, 1024, 4787, fc2b);
}

// Round 12
// 1043.037 us; speedup vs baseline: 1.0848x; 1.0008x over previous
//
#include <hip/hip_runtime.h>

typedef short short8v __attribute__((ext_vector_type(8)));
typedef float f32x4 __attribute__((ext_vector_type(4)));
typedef _Float16 h4v __attribute__((ext_vector_type(4)));

__device__ __forceinline__ unsigned short f2bf(float f){
  unsigned int u = __float_as_uint(f);
  u += 0x7fffu + ((u >> 16) & 1u);
  return (unsigned short)(u >> 16);
}
__device__ __forceinline__ float bf2f(unsigned short h){
  return __uint_as_float(((unsigned int)h) << 16);
}
union H2F { unsigned short u; _Float16 h; };
__device__ __forceinline__ float fp16f(unsigned short b){ H2F t; t.u = b; return (float)t.h; }
__device__ __forceinline__ float fast_tanh(float x){
  // exact at +/-inf (expf -> inf/0 => +/-1); ~1e-7 abs err, << bf16 rounding
  return 1.f - 2.f / (1.f + __expf(2.f * x));
}

typedef __attribute__((address_space(1))) const unsigned int gu32;
typedef __attribute__((address_space(3))) unsigned int lu32;
__device__ __forceinline__ void gl16(const void* g, void* l){
  __builtin_amdgcn_global_load_lds((gu32*)g, (lu32*)l, 16, 0, 0);
}

// ========== 256x256 GEMM: C = A @ B^T, bf16 in; 4-phase staggered prefetch (proven schedule) ==========
// EPI 0: +bias -> f32 (fc2) | EPI 3: +bias -> fp16 unit-packed (G)
template<int EPI>
__global__ __launch_bounds__(512, 2)
void gemm256(const unsigned short* __restrict__ A, const unsigned short* __restrict__ B,
             void* __restrict__ Cout, int M, int N, int K, int lda, int ldb, int ldc,
             const float* __restrict__ bias)
{
  __shared__ __align__(16) unsigned short As[2 * 2 * 256 * 32];   // 64 KB
  __shared__ __align__(16) unsigned short Bs[2 * 2 * 256 * 32];   // 64 KB

  const int tid = threadIdx.x;
  const int gx = gridDim.x;
  const int nwg = gx * gridDim.y;
  int dd = blockIdx.y * gx + blockIdx.x;
  int q8 = nwg >> 3, r8 = nwg & 7, xc = dd & 7, t8 = dd >> 3;
  int Lid = (xc < r8 ? xc * (q8 + 1) : r8 * (q8 + 1) + (xc - r8) * q8) + t8;
  const int bcol = (Lid % gx) * 256;
  const int brow = (Lid / gx) * 256;

  const int l = tid & 63, w = tid >> 6;
  const int wr = w >> 2;                 // M half (0..1)
  const int wn = w & 3;                  // N quarter (0..3)
  const int r16 = l & 15, kg = l >> 4;
  const int swz = (r16 >> 1) & 3;
  const int srow4 = l >> 2, sblk = l & 3;
  const int scol = (sblk ^ ((l >> 3) & 3)) * 8;

  const int kz = blockIdx.z * K;
  const unsigned short* Ag = A + (size_t)(brow + w * 32 + srow4) * lda + kz + scol;
  const unsigned short* Bg = B + (size_t)(bcol + w * 32 + srow4) * ldb + kz + scol;
  unsigned short* Asd = As + w * 1024;
  unsigned short* Bsd = Bs + w * 1024;

#define STA(buf, kh, kt) do { \
    gl16(Ag + (size_t)(kt) * 64 + (kh) * 32, Asd + (buf) * 16384 + (kh) * 8192); \
    gl16(Ag + (size_t)(kt) * 64 + (kh) * 32 + (size_t)16 * lda, Asd + (buf) * 16384 + (kh) * 8192 + 512); \
  } while (0)
#define STB(buf, kh, kt) do { \
    gl16(Bg + (size_t)(kt) * 64 + (kh) * 32, Bsd + (buf) * 16384 + (kh) * 8192); \
    gl16(Bg + (size_t)(kt) * 64 + (kh) * 32 + (size_t)16 * ldb, Bsd + (buf) * 16384 + (kh) * 8192 + 512); \
  } while (0)

  const unsigned short* Ard = As + (wr * 128 + r16) * 32 + ((kg ^ swz) * 8);
  const unsigned short* Brd = Bs + (wn * 64 + r16) * 32 + ((kg ^ swz) * 8);

  f32x4 acc[8][4];
  #pragma unroll
  for (int m = 0; m < 8; m++)
    #pragma unroll
    for (int nn = 0; nn < 4; nn++) { f32x4 z = {0.f, 0.f, 0.f, 0.f}; acc[m][nn] = z; }

  short8v af[4], bfr[4];

#define LDA4(c, kk, mq) { \
    _Pragma("unroll") for (int i = 0; i < 4; i++) \
      af[i] = *(const short8v*)(Ard + (c) * 16384 + (kk) * 8192 + ((mq) * 4 + i) * 512); }
#define LDB4(c, kk) { \
    _Pragma("unroll") for (int nn = 0; nn < 4; nn++) \
      bfr[nn] = *(const short8v*)(Brd + (c) * 16384 + (kk) * 8192 + nn * 512); }
#define MFMAQ(mq) { \
    __builtin_amdgcn_s_setprio(1); \
    _Pragma("unroll") for (int i = 0; i < 4; i++) { \
      _Pragma("unroll") for (int nn = 0; nn < 4; nn++) \
        acc[(mq) * 4 + i][nn] = __builtin_amdgcn_mfma_f32_16x16x32_bf16(af[i], bfr[nn], acc[(mq) * 4 + i][nn], 0, 0, 0); \
    } \
    __builtin_amdgcn_s_setprio(0); }

  const int nk = K >> 6;
  STA(0, 0, 0); STB(0, 0, 0); STA(0, 1, 0); STB(0, 1, 0);
  asm volatile("s_waitcnt vmcnt(4)" ::: "memory");
  __builtin_amdgcn_s_barrier();
  __builtin_amdgcn_sched_barrier(0);

  for (int j = 0; j < nk; j++) {
    const int c = j & 1, nb = c ^ 1;
    const bool pf = (j + 1 < nk);
    // phase 1
    LDB4(c, 0); LDA4(c, 0, 0);
    if (pf) STA(nb, 0, j + 1);
    __builtin_amdgcn_s_barrier();
    MFMAQ(0);
    __builtin_amdgcn_s_barrier();
    // phase 2
    LDA4(c, 0, 1);
    if (pf) STB(nb, 0, j + 1);
    __builtin_amdgcn_s_barrier();
    MFMAQ(1);
    if (pf) asm volatile("s_waitcnt vmcnt(4)" ::: "memory");
    else    asm volatile("s_waitcnt vmcnt(0)" ::: "memory");
    __builtin_amdgcn_s_barrier();
    __builtin_amdgcn_sched_barrier(0);
    // phase 3
    LDB4(c, 1); LDA4(c, 1, 0);
    if (pf) STA(nb, 1, j + 1);
    __builtin_amdgcn_s_barrier();
    MFMAQ(0);
    __builtin_amdgcn_s_barrier();
    // phase 4
    LDA4(c, 1, 1);
    if (pf) STB(nb, 1, j + 1);
    __builtin_amdgcn_s_barrier();
    MFMAQ(1);
    if (pf) asm volatile("s_waitcnt vmcnt(4)" ::: "memory");
    __builtin_amdgcn_s_barrier();
    __builtin_amdgcn_sched_barrier(0);
  }
#undef STA
#undef STB
#undef LDA4
#undef LDB4
#undef MFMAQ

  // C/D map: col = lane&15, row = (lane>>4)*4 + reg
  #pragma unroll
  for (int m = 0; m < 8; m++) {
    const int row0 = brow + wr * 128 + m * 16 + kg * 4;
    #pragma unroll
    for (int nn = 0; nn < 4; nn++) {
      const int col = bcol + wn * 64 + nn * 16 + r16;
      if (col < N) {
        const float bv = bias[col];
        #pragma unroll
        for (int rr = 0; rr < 4; rr++) {
          const int row = row0 + rr;
          if (row < M) {
            float val = acc[m][nn][rr] + bv;
            if (EPI == 3) {
              int dL = col >> 11, rc = col & 2047;
              int cg = rc >> 6, g = (rc >> 4) & 3, u = rc & 15;
              int pc = (dL << 11) + (((cg << 4) + u) << 2) + g;
              ((_Float16*)Cout)[(size_t)row * ldc + pc] = (_Float16)val;
            } else {
              ((float*)Cout)[(size_t)row * ldc + col] = val;
            }
          }
        }
      }
    }
  }
}

// ========== fc1 GEMM with fused f32->bf16 A conversion (proven round-5 schedule) ==========
__global__ __launch_bounds__(512, 2)
void gemm256fA(const float* __restrict__ A, const unsigned short* __restrict__ B,
               _Float16* __restrict__ Cout, int M, int N, int K, int lda, int ldb, int ldc,
               int nvalid)
{
  __shared__ __align__(16) unsigned short As[2 * 2 * 256 * 32];   // 64 KB
  __shared__ __align__(16) unsigned short Bs[2 * 2 * 256 * 32];   // 64 KB

  const int tid = threadIdx.x;
  const int gx = gridDim.x;
  const int nwg = gx * gridDim.y;
  int dd = blockIdx.y * gx + blockIdx.x;
  int q8 = nwg >> 3, r8 = nwg & 7, xc = dd & 7, t8 = dd >> 3;
  int Lid = (xc < r8 ? xc * (q8 + 1) : r8 * (q8 + 1) + (xc - r8) * q8) + t8;
  const int bcol = (Lid % gx) * 256;
  const int brow = (Lid / gx) * 256;

  const int l = tid & 63, w = tid >> 6;
  const int wr = w >> 2;
  const int wn = w & 3;
  const int r16 = l & 15, kg = l >> 4;
  const int swz = (r16 >> 1) & 3;
  const int srow4 = l >> 2, sblk = l & 3;
  const int scol = (sblk ^ ((l >> 3) & 3)) * 8;

  const int kz = blockIdx.z * K;
  const unsigned short* Bg = B + (size_t)(bcol + w * 32 + srow4) * ldb + kz + scol;
  unsigned short* Bsd = Bs + w * 1024;

#define STB(buf, kh, kt) do { \
    gl16(Bg + (size_t)(kt) * 64 + (kh) * 32, Bsd + (buf) * 16384 + (kh) * 8192); \
    gl16(Bg + (size_t)(kt) * 64 + (kh) * 32 + (size_t)16 * ldb, Bsd + (buf) * 16384 + (kh) * 8192 + 512); \
  } while (0)

  // --- A reg-staging geometry: lane -> (row, 8-f32 granule), q = 0..3 ---
  const int rsel8 = l >> 3;         // 0..7 row within 8-row group
  const int g8 = l & 7;             // granule of 8 consecutive f32 within the 64-k tile
  unsigned long long abase[4];
  int dstA[4];
  #pragma unroll
  for (int q = 0; q < 4; q++) {
    int row_local = w * 32 + q * 8 + rsel8;
    int rowA = brow + row_local;
    if (rowA >= nvalid) rowA = nvalid - 1;
    abase[q] = (unsigned long long)(A + (size_t)rowA * lda + kz + g8 * 8);
    int kh = g8 >> 2, gA = g8 & 3, swi = (row_local >> 1) & 3;
    dstA[q] = kh * 8192 + row_local * 32 + ((gA ^ swi) * 8);
  }

  const unsigned short* Ard = As + (wr * 128 + r16) * 32 + ((kg ^ swz) * 8);
  const unsigned short* Brd = Bs + (wn * 64 + r16) * 32 + ((kg ^ swz) * 8);

  f32x4 acc[8][4];
  #pragma unroll
  for (int m = 0; m < 8; m++)
    #pragma unroll
    for (int nn = 0; nn < 4; nn++) { f32x4 z = {0.f, 0.f, 0.f, 0.f}; acc[m][nn] = z; }

  short8v af[4], bfr[4];
  f32x4 ar[4][2];

#define ALOAD(kt) { \
    _Pragma("unroll") for (int q = 0; q < 4; q++) { \
      unsigned long long aq = abase[q] + (unsigned long long)(kt) * 256; \
      asm volatile("global_load_dwordx4 %0, %1, off" : "=v"(ar[q][0]) : "v"(aq) : "memory"); \
      asm volatile("global_load_dwordx4 %0, %1, off offset:16" : "=v"(ar[q][1]) : "v"(aq) : "memory"); \
    } }
#define AWRITE(buf) { \
    _Pragma("unroll") for (int q = 0; q < 4; q++) { \
      unsigned int d0_, d1_, d2_, d3_; \
      asm("v_cvt_pk_bf16_f32 %0, %1, %2" : "=v"(d0_) : "v"(ar[q][0][0]), "v"(ar[q][0][1])); \
      asm("v_cvt_pk_bf16_f32 %0, %1, %2" : "=v"(d1_) : "v"(ar[q][0][2]), "v"(ar[q][0][3])); \
      asm("v_cvt_pk_bf16_f32 %0, %1, %2" : "=v"(d2_) : "v"(ar[q][1][0]), "v"(ar[q][1][1])); \
      asm("v_cvt_pk_bf16_f32 %0, %1, %2" : "=v"(d3_) : "v"(ar[q][1][2]), "v"(ar[q][1][3])); \
      uint4 pv_; pv_.x = d0_; pv_.y = d1_; pv_.z = d2_; pv_.w = d3_; \
      *(uint4*)(As + (buf) * 16384 + dstA[q]) = pv_; \
    } }

  const int nk = K >> 6;
  // prologue: A tile0 (reg) + B tile0 (gl16, both pieces)
  ALOAD(0);
  STB(0, 0, 0); STB(0, 1, 0);
  asm volatile("s_waitcnt vmcnt(4)" ::: "memory");   // retire A loads (4 B gl16 remain)
  __builtin_amdgcn_sched_barrier(0);
  AWRITE(0);
  asm volatile("s_waitcnt vmcnt(0) lgkmcnt(0)" ::: "memory");
  __builtin_amdgcn_s_barrier();
  __builtin_amdgcn_sched_barrier(0);

#define LDA4(c, kk, mq) { \
    _Pragma("unroll") for (int i = 0; i < 4; i++) \
      af[i] = *(const short8v*)(Ard + (c) * 16384 + (kk) * 8192 + ((mq) * 4 + i) * 512); }
#define LDB4(c, kk) { \
    _Pragma("unroll") for (int nn = 0; nn < 4; nn++) \
      bfr[nn] = *(const short8v*)(Brd + (c) * 16384 + (kk) * 8192 + nn * 512); }
#define MFMAQ(mq) { \
    __builtin_amdgcn_s_setprio(1); \
    _Pragma("unroll") for (int i = 0; i < 4; i++) { \
      _Pragma("unroll") for (int nn = 0; nn < 4; nn++) \
        acc[(mq) * 4 + i][nn] = __builtin_amdgcn_mfma_f32_16x16x32_bf16(af[i], bfr[nn], acc[(mq) * 4 + i][nn], 0, 0, 0); \
    } \
    __builtin_amdgcn_s_setprio(0); }

  for (int j = 0; j < nk; j++) {
    const int c = j & 1, nb = c ^ 1;
    const bool pf = (j + 1 < nk);
    // phase 1: issue A loads for j+1 (oldest VMEM, 8 ops)
    LDB4(c, 0); LDA4(c, 0, 0);
    if (pf) ALOAD(j + 1);
    __builtin_amdgcn_s_barrier();
    MFMAQ(0);
    __builtin_amdgcn_s_barrier();
    // phase 2: stage BOTH B pieces for j+1 (4 gl16)
    LDA4(c, 0, 1);
    if (pf) { STB(nb, 0, j + 1); STB(nb, 1, j + 1); }
    __builtin_amdgcn_s_barrier();
    MFMAQ(1);
    __builtin_amdgcn_s_barrier();
    __builtin_amdgcn_sched_barrier(0);
    // phase 3: retire A loads (2 phases of slack), convert + b128 write
    LDB4(c, 1); LDA4(c, 1, 0);
    if (pf) {
      asm volatile("s_waitcnt vmcnt(4)" ::: "memory");
      __builtin_amdgcn_sched_barrier(0);
      AWRITE(nb);
    }
    __builtin_amdgcn_s_barrier();
    MFMAQ(0);
    __builtin_amdgcn_s_barrier();
    // phase 4: drain B (staged 2 phases ago) + ds_writes before the buffer-swap barrier
    LDA4(c, 1, 1);
    __builtin_amdgcn_s_barrier();
    MFMAQ(1);
    asm volatile("s_waitcnt vmcnt(0) lgkmcnt(0)" ::: "memory");
    __builtin_amdgcn_s_barrier();
    __builtin_amdgcn_sched_barrier(0);
  }
#undef STB
#undef ALOAD
#undef AWRITE
#undef LDA4
#undef LDB4
#undef MFMAQ

  // epilogue: raw fp16 partial
  #pragma unroll
  for (int m = 0; m < 8; m++) {
    const int row0 = brow + wr * 128 + m * 16 + kg * 4;
    #pragma unroll
    for (int nn = 0; nn < 4; nn++) {
      const int col = bcol + wn * 64 + nn * 16 + r16;
      if (col < N) {
        #pragma unroll
        for (int rr = 0; rr < 4; rr++) {
          const int row = row0 + rr;
          if (row < M)
            Cout[(size_t)blockIdx.z * M * ldc + (size_t)row * ldc + col] = (_Float16)(acc[m][nn][rr]);
        }
      }
    }
  }
}

// ========== fc1 split-K reduce: h = relu(P0+P1+P2+bias) -> bf16, fused BN partial sums ==========
__global__ __launch_bounds__(256) void fc1_reduce(const _Float16* __restrict__ P, const float* __restrict__ bias,
                                                  unsigned short* __restrict__ h, float* __restrict__ part,
                                                  int n, int mpad) {
  int b = blockIdx.x, tid = threadIdx.x;
  int c0 = tid * 4;
  float4 bsv = *(const float4*)(bias + c0);
  float s[4] = {0,0,0,0}, qq[4] = {0,0,0,0};
  int rbeg = b * 32;
  for (int r = rbeg; r < rbeg + 32; r++) {
    h4v a0 = *(const h4v*)(P + (size_t)r * 1024 + c0);
    h4v a1 = *(const h4v*)(P + ((size_t)mpad + r) * 1024 + c0);
    h4v a2 = *(const h4v*)(P + ((size_t)2 * mpad + r) * 1024 + c0);
    float v0 = fmaxf((float)a0[0] + (float)a1[0] + (float)a2[0] + bsv.x, 0.f);
    float v1 = fmaxf((float)a0[1] + (float)a1[1] + (float)a2[1] + bsv.y, 0.f);
    float v2 = fmaxf((float)a0[2] + (float)a1[2] + (float)a2[2] + bsv.z, 0.f);
    float v3 = fmaxf((float)a0[3] + (float)a1[3] + (float)a2[3] + bsv.w, 0.f);
    if (r < n) {
      s[0] += v0; qq[0] += v0 * v0;
      s[1] += v1; qq[1] += v1 * v1;
      s[2] += v2; qq[2] += v2 * v2;
      s[3] += v3; qq[3] += v3 * v3;
    }
    *(ushort4*)(h + (size_t)r * 1024 + c0) = make_ushort4(f2bf(v0), f2bf(v1), f2bf(v2), f2bf(v3));
  }
  float* pp = part + (size_t)b * 2048;
  #pragma unroll
  for (int k = 0; k < 4; k++) { pp[(c0 + k) * 2] = s[k]; pp[(c0 + k) * 2 + 1] = qq[k]; }
}

// ================= persistent fused bidirectional LSTM =================
__global__ __launch_bounds__(256, 1)
void lstm_persist(const unsigned short* __restrict__ whhc, const unsigned short* __restrict__ bcp,
                  const _Float16* __restrict__ G,
                  const int* __restrict__ gf, const int* __restrict__ gb, const int* __restrict__ sb,
                  unsigned short* __restrict__ hst,
                  unsigned short* __restrict__ lfeat, int* __restrict__ flags)
{
  __shared__ __align__(16) unsigned short Bsh[128 * 512];   // 128 KB resident whh tile
  const int tid = threadIdx.x;
  const int l = tid & 63, w = tid >> 6;
  const int b = blockIdx.x;
  const int grp = b & 15;          // (d, rg)
  const int c = b >> 4;            // 0..15 h-col block
  const int d = grp >> 3;
  const int rowbase = d * 512 + (grp & 7) * 64;
  const int r16 = l & 15, kg = l >> 4;
  const int swzl = (r16 & 7) * 8;
  const int hu0 = c * 32 + r16;

  const unsigned short* Bsrc = whhc + ((size_t)(d * 2048 + c * 128)) * 512;
  #pragma unroll
  for (int i = 0; i < 32; i++) {
    int rr = w * 32 + i;
    gl16(Bsrc + (size_t)rr * 512 + ((l * 8) ^ ((rr & 7) * 8)), Bsh + rr * 512);
  }
  asm volatile("s_waitcnt vmcnt(0)");
  __syncthreads();

  float creg[2][4];
  #pragma unroll
  for (int m = 0; m < 2; m++)
    #pragma unroll
    for (int rr = 0; rr < 4; rr++) creg[m][rr] = 0.f;

  const size_t stbase = (size_t)(((grp * 4 + w) * 16 + c) * 4 + (r16 >> 3)) * 128 + (size_t)kg * 32 + (r16 & 7);
  const size_t ldbase = ((size_t)(grp * 64 + w * 16) * 1024) + (size_t)l * 16;

  for (int t = 0; t < 32; t++) {
    ushort4 gv[2][4];
    int scv[4];
    #pragma unroll
    for (int rr = 0; rr < 4; rr++) {
      int row = rowbase + w * 16 + kg * 4 + rr;
      int sq = row & 511;
      int gi = d ? gb[sq * 32 + t] : gf[sq * 32 + t];
      const unsigned short* src = (gi >= 0)
          ? (const unsigned short*)G + ((size_t)gi * 4096 + (d << 11))
          : bcp + (d << 11);
      gv[0][rr] = *(const ushort4*)(src + hu0 * 4);
      gv[1][rr] = *(const ushort4*)(src + (hu0 + 16) * 4);
      scv[rr] = d ? sb[sq * 32 + t] : gi;
    }

    if (t > 0) {
      while (true) {
        int fv = 0x7fffffff;
        if (l < 16)
          fv = __hip_atomic_load(flags + ((grp * 16 + l) << 5), __ATOMIC_RELAXED, __HIP_MEMORY_SCOPE_AGENT);
        if (__all(fv >= t)) break;
        __builtin_amdgcn_s_sleep(1);
      }
    }
    asm volatile("" ::: "memory");

    const unsigned short* hp = hst + (size_t)(t & 1) * 524288;
    unsigned short* hn = hst + (size_t)((t + 1) & 1) * 524288;

    short8v av[16];
    {
      unsigned long long a64 = (unsigned long long)((const char*)hp + ldbase);
      #pragma unroll
      for (int kq = 0; kq < 4; kq++) {
        unsigned long long aq = a64 + (unsigned long long)kq * 4096;
        asm volatile("global_load_dwordx4 %0, %1, off offset:0 sc0 sc1"
                     : "=v"(av[kq * 4 + 0]) : "v"(aq) : "memory");
        asm volatile("global_load_dwordx4 %0, %1, off offset:1024 sc0 sc1"
                     : "=v"(av[kq * 4 + 1]) : "v"(aq) : "memory");
        asm volatile("global_load_dwordx4 %0, %1, off offset:2048 sc0 sc1"
                     : "=v"(av[kq * 4 + 2]) : "v"(aq) : "memory");
        asm volatile("global_load_dwordx4 %0, %1, off offset:3072 sc0 sc1"
                     : "=v"(av[kq * 4 + 3]) : "v"(aq) : "memory");
      }
    }
    asm volatile("s_waitcnt vmcnt(0)" ::: "memory");

    f32x4 acc[8];
    #pragma unroll
    for (int nn = 0; nn < 8; nn++) { f32x4 z = {0.f, 0.f, 0.f, 0.f}; acc[nn] = z; }

    #pragma unroll
    for (int kc = 0; kc < 8; kc++) {
      short8v bv[8][2];
      #pragma unroll
      for (int nn = 0; nn < 8; nn++)
        #pragma unroll
        for (int kk = 0; kk < 2; kk++)
          bv[nn][kk] = *(const short8v*)(Bsh + (nn * 16 + r16) * 512 + ((kc * 64 + kk * 32 + kg * 8) ^ swzl));
      #pragma unroll
      for (int kk = 0; kk < 2; kk++)
        #pragma unroll
        for (int nn = 0; nn < 8; nn++)
          acc[nn] = __builtin_amdgcn_mfma_f32_16x16x32_bf16(av[kc * 2 + kk], bv[nn][kk], acc[nn], 0, 0, 0);
    }

    unsigned long long ha = (unsigned long long)((char*)hn + stbase * 2);
    #pragma unroll
    for (int cgl = 0; cgl < 2; cgl++) {
      const int hu = hu0 + cgl * 16;
      #pragma unroll
      for (int reg = 0; reg < 4; reg++) {
        float g_i = acc[cgl * 4 + 0][reg] + fp16f(gv[cgl][reg].x);
        float g_f = acc[cgl * 4 + 1][reg] + fp16f(gv[cgl][reg].y);
        float g_g = acc[cgl * 4 + 2][reg] + fp16f(gv[cgl][reg].z);
        float g_o = acc[cgl * 4 + 3][reg] + fp16f(gv[cgl][reg].w);
        float si = 1.f / (1.f + __expf(-g_i));
        float sf = 1.f / (1.f + __expf(-g_f));
        float so = 1.f / (1.f + __expf(-g_o));
        float cn = sf * creg[cgl][reg] + si * fast_tanh(g_g);
        float hnv = so * fast_tanh(cn);
        creg[cgl][reg] = cn;
        unsigned int hb = f2bf(hnv);
        if (cgl == 0) {
          if (reg == 0) asm volatile("global_store_short %0, %1, off offset:0 sc0 sc1" :: "v"(ha), "v"(hb) : "memory");
          if (reg == 1) asm volatile("global_store_short %0, %1, off offset:16 sc0 sc1" :: "v"(ha), "v"(hb) : "memory");
          if (reg == 2) asm volatile("global_store_short %0, %1, off offset:32 sc0 sc1" :: "v"(ha), "v"(hb) : "memory");
          if (reg == 3) asm volatile("global_store_short %0, %1, off offset:48 sc0 sc1" :: "v"(ha), "v"(hb) : "memory");
        } else {
          if (reg == 0) asm volatile("global_store_short %0, %1, off offset:512 sc0 sc1" :: "v"(ha), "v"(hb) : "memory");
          if (reg == 1) asm volatile("global_store_short %0, %1, off offset:528 sc0 sc1" :: "v"(ha), "v"(hb) : "memory");
          if (reg == 2) asm volatile("global_store_short %0, %1, off offset:544 sc0 sc1" :: "v"(ha), "v"(hb) : "memory");
          if (reg == 3) asm volatile("global_store_short %0, %1, off offset:560 sc0 sc1" :: "v"(ha), "v"(hb) : "memory");
        }
        int sc = scv[reg];
        if (sc >= 0) lfeat[(size_t)sc * 1024 + d * 512 + hu] = f2bf(hnv);
      }
    }

    __syncthreads();
    if (t < 31 && tid == 0)
      __hip_atomic_store(flags + ((grp * 16 + c) << 5), t + 1, __ATOMIC_RELAXED, __HIP_MEMORY_SCOPE_AGENT);
  }
}

// ================= merged prologue: conv w1 + conv w2 + build_whh + prep_tables + zeroing =================
__device__ __forceinline__ void conv_seg(const float* __restrict__ src, unsigned short* __restrict__ dst,
                                         size_t nvalid, size_t total, int vb, int nb) {
  size_t stride = (size_t)nb * 2048;
  for (size_t i = ((size_t)vb * 256 + threadIdx.x) * 8; i < total; i += stride) {
    unsigned short o[8];
    if (i + 8 <= nvalid) {
      float4 a = *(const float4*)(src + i);
      float4 b = *(const float4*)(src + i + 4);
      o[0] = f2bf(a.x); o[1] = f2bf(a.y); o[2] = f2bf(a.z); o[3] = f2bf(a.w);
      o[4] = f2bf(b.x); o[5] = f2bf(b.y); o[6] = f2bf(b.z); o[7] = f2bf(b.w);
    } else {
      #pragma unroll
      for (int j = 0; j < 8; j++) o[j] = (i + j < nvalid) ? f2bf(src[i + j]) : (unsigned short)0;
    }
    *(ushort4*)(dst + i) = make_ushort4(o[0], o[1], o[2], o[3]);
    *(ushort4*)(dst + i + 4) = make_ushort4(o[4], o[5], o[6], o[7]);
  }
}

__global__ __launch_bounds__(256)
void prep_all(const float* __restrict__ fc1w, unsigned short* __restrict__ w1_h,
              const float* __restrict__ fc2w, unsigned short* __restrict__ w2_h,
              const float* __restrict__ whhf, const float* __restrict__ whhb,
              unsigned short* __restrict__ whhc,
              const int* __restrict__ seq_idx, const int* __restrict__ lengths,
              int* __restrict__ gf, int* __restrict__ gb, int* __restrict__ sb,
              unsigned short* __restrict__ hstate, int* __restrict__ flags)
{
  const int b = blockIdx.x;
  if (b < 1024) {
    // conv w1: 1024x13824 f32 -> bf16
    conv_seg(fc1w, w1_h, (size_t)1024 * 13824, (size_t)1024 * 13824, b, 1024);
  } else if (b < 1280) {
    // conv w2: 4787x1024 valid of 4864x1024
    conv_seg(fc2w, w2_h, (size_t)4787 * 1024, (size_t)4864 * 1024, b - 1024, 256);
  } else if (b < 2304) {
    // build_whh: orow = d*2048 + c*128 + L, L = cgl*64 + g*16 + u -> src row g*512 + (c*32+cgl*16+u)
    int cidx = (b - 1280) * 256 + threadIdx.x;
    int orow = cidx >> 6, k0 = (cidx & 63) * 8;
    int dir = orow >> 11, j = orow & 2047;
    int cc = j >> 7, L = j & 127;
    int cgl = L >> 6, g = (L >> 4) & 3, u = L & 15;
    int hunit = cc * 32 + cgl * 16 + u;
    const float* src = (dir ? whhb : whhf) + (size_t)(g * 512 + hunit) * 512 + k0;
    unsigned short* dst = whhc + (size_t)orow * 512 + k0;
    float4 a = *(const float4*)(src);
    float4 bq = *(const float4*)(src + 4);
    dst[0] = f2bf(a.x); dst[1] = f2bf(a.y); dst[2] = f2bf(a.z); dst[3] = f2bf(a.w);
    dst[4] = f2bf(bq.x); dst[5] = f2bf(bq.y); dst[6] = f2bf(bq.z); dst[7] = f2bf(bq.w);
  } else if (b < 2368) {
    // prep_tables
    int idx = (b - 2304) * 256 + threadIdx.x;
    int s = idx >> 5, t = idx & 31;
    int len = lengths[s];
    gf[idx] = (t < len) ? seq_idx[idx] : -1;
    int rb = len - 1 - t;
    gb[idx] = seq_idx[(s << 5) + (rb < 0 ? 0 : rb)];
    sb[idx] = (t < len) ? seq_idx[(s << 5) + (len - 1 - t)] : -1;
  } else if (b < 2496) {
    // zero hstate: 2*1024*512*2 B = 131072 x 16B
    uint4 z = {0u, 0u, 0u, 0u};
    uint4* p = (uint4*)hstate;
    for (int i = (b - 2368) * 256 + threadIdx.x; i < 131072; i += 128 * 256)
      p[i] = z;
  } else {
    // zero flags: 256*32*4 B = 2048 x 16B (8 blocks x 256 threads, one uint4 each)
    uint4 z = {0u, 0u, 0u, 0u};
    int i = (b - 2496) * 256 + threadIdx.x;
    if (i < 2048) ((uint4*)flags)[i] = z;
  }
}

// ================= remaining helpers =================
__global__ __launch_bounds__(256) void bn_final(const float* __restrict__ part, const float* __restrict__ gamma,
                                                const float* __restrict__ beta, float* __restrict__ scale,
                                                float* __restrict__ shift, int M, int nb) {
  int c = blockIdx.x * 256 + threadIdx.x;
  float s = 0.f, q = 0.f;
  for (int b = 0; b < nb; b++) { s += part[(size_t)b * 2048 + c * 2]; q += part[(size_t)b * 2048 + c * 2 + 1]; }
  float mean = s / (float)M;
  float var = q / (float)M - mean * mean;
  float sc = gamma[c] * rsqrtf(var + 1e-5f);
  scale[c] = sc; shift[c] = beta[c] - mean * sc;
}

__global__ __launch_bounds__(256) void build_wih(const float* __restrict__ wf, const float* __restrict__ wb,
                                                 const float* __restrict__ bihf, const float* __restrict__ bhhf,
                                                 const float* __restrict__ bihb, const float* __restrict__ bhhb,
                                                 const float* __restrict__ scale, const float* __restrict__ shift,
                                                 unsigned short* __restrict__ wcdst, float* __restrict__ bc,
                                                 _Float16* __restrict__ bcp) {
  int orow = blockIdx.x * 4 + (threadIdx.x >> 6);
  int l = threadIdx.x & 63;
  int dir = orow >> 11, j = orow & 2047;
  int cc = j >> 6, jj = j & 63, g = jj >> 4, u = jj & 15;
  int srow = g * 512 + cc * 16 + u;
  const float* src = (dir ? wb : wf) + (size_t)srow * 1024;
  unsigned short* dst = wcdst + (size_t)orow * 1024;
  float sacc = 0.f;
  #pragma unroll
  for (int jv = 0; jv < 16; jv++) {
    int k = l + jv * 64;
    float v = src[k];
    sacc += shift[k] * v;
    dst[k] = f2bf(v * scale[k]);
  }
  #pragma unroll
  for (int o2 = 32; o2 > 0; o2 >>= 1) sacc += __shfl_down(sacc, o2);
  if (l == 0) {
    float bb = (dir ? (bihb[srow] + bhhb[srow]) : (bihf[srow] + bhhf[srow])) + sacc;
    bc[orow] = bb;
    int pc = (dir << 11) + (((cc << 4) + u) << 2) + g;
    bcp[pc] = (_Float16)bb;
  }
}

extern "C" void kernel_launch(void* const* d_in, const int* in_sizes, int n_in,
                              void* d_out, int out_size, void* d_ws, size_t ws_size,
                              hipStream_t stream) {
  const float* x     = (const float*)d_in[0];
  const float* fc1w  = (const float*)d_in[1];
  const float* fc1b  = (const float*)d_in[2];
  const float* gamma = (const float*)d_in[3];
  const float* beta  = (const float*)d_in[4];
  const float* fc2w  = (const float*)d_in[5];
  const float* fc2b  = (const float*)d_in[6];
  const float* wihf  = (const float*)d_in[7];
  const float* whhf  = (const float*)d_in[8];
  const float* bihf  = (const float*)d_in[9];
  const float* bhhf  = (const float*)d_in[10];
  const float* wihb  = (const float*)d_in[11];
  const float* whhb  = (const float*)d_in[12];
  const float* bihb  = (const float*)d_in[13];
  const float* bhhb  = (const float*)d_in[14];
  const int* seq_idx = (const int*)d_in[15];
  const int* lengths = (const int*)d_in[16];
  float* out = (float*)d_out;

  const int n = in_sizes[0] / 13824;           // 9121
  const int mt = (n + 255) / 256;              // 36 M-tiles of 256
  const int mpad = mt * 256;                   // 9216

  char* ws = (char*)d_ws;
  size_t off = 0;
  auto alloc = [&](size_t bytes) -> void* {
    void* p = ws + off; off += (bytes + 255) & ~(size_t)255; return p;
  };
  unsigned short* w1_h = (unsigned short*)alloc((size_t)1024 * 13824 * 2);
  unsigned short* w2_h = (unsigned short*)alloc((size_t)4864 * 1024 * 2);
  unsigned short* h    = (unsigned short*)alloc((size_t)mpad * 1024 * 2);
  _Float16*       G    = (_Float16*)alloc((size_t)mpad * 4096 * 2);  // also aliased as split-K partials
  unsigned short* wihc = (unsigned short*)alloc((size_t)4096 * 1024 * 2);
  unsigned short* whhc = (unsigned short*)alloc((size_t)4096 * 512 * 2);
  float* bias_c = (float*)alloc(4096 * 4);
  _Float16* bias_p = (_Float16*)alloc(4096 * 2);
  unsigned short* lfeat  = (unsigned short*)alloc((size_t)mpad * 1024 * 2);
  unsigned short* hstate = (unsigned short*)alloc((size_t)2 * 1024 * 512 * 2);
  float* part   = (float*)alloc((size_t)(mpad / 32) * 2048 * 4);
  float* scale  = (float*)alloc(1024 * 4);
  float* shift  = (float*)alloc(1024 * 4);
  int* gf  = (int*)alloc(16384 * 4);
  int* gb  = (int*)alloc(16384 * 4);
  int* sb  = (int*)alloc(16384 * 4);
  int* flags = (int*)alloc(256 * 32 * 4);

  _Float16* P16 = (_Float16*)G;   // fc1 split-K fp16 partials [3][mpad][1024] (56.6 MB <= G size 75.5 MB)

  dim3 blk(256);
  dim3 blk5(512);

  // merged prologue: conv w1 + conv w2 + build_whh + prep_tables + hstate/flags zero
  prep_all<<<2504, blk, 0, stream>>>(fc1w, w1_h, fc2w, w2_h, whhf, whhb, whhc,
                                     seq_idx, lengths, gf, gb, sb, hstate, flags);

  // fc1 split-K with fused f32->bf16 A conversion: P16[z] = x @ w1^T (K chunk z), z in {0,1,2}
  gemm256fA<<<dim3(4, mt, 3), blk5, 0, stream>>>(
      x, w1_h, P16, mpad, 1024, 4608, 13824, 13824, 1024, n);

  // reduce + bias + relu -> h bf16, fused BN partial sums
  fc1_reduce<<<mpad / 32, blk, 0, stream>>>(P16, fc1b, h, part, n, mpad);
  bn_final<<<4, blk, 0, stream>>>(part, gamma, beta, scale, shift, n, mpad / 32);
  build_wih<<<1024, blk, 0, stream>>>(wihf, wihb, bihf, bhhf, bihb, bhhb, scale, shift, wihc, bias_c, bias_p);

  // G = feats @ wih_c^T + bias_c -> fp16, unit-packed (BN folded; overwrites P16 after it's consumed)
  gemm256<3><<<dim3(16, mt), blk5, 0, stream>>>(
      h, wihc, G, n, 4096, 1024, 1024, 1024, 4096, bias_c);

  // fused persistent bidirectional LSTM (32 steps)
  lstm_persist<<<256, blk, 0, stream>>>(whhc, (const unsigned short*)bias_p, G, gf, gb, sb,
                                        hstate, lfeat, flags);

  // fc2: out = lstm_feats @ fc2w^T + b
  gemm256<0><<<dim3(19, mt), blk5, 0, stream>>>(
      lfeat, w2_h, out, n, 4787, 1024, 1024, 1024, 4787, fc2b);
}